// Round 3
// baseline (1244.044 us; speedup 1.0000x reference)
//
#include <hip/hip_runtime.h>
#include <math.h>

// Shapes (fixed by the problem)
#define NBATCH 128
#define NPTS   196     // 14*14 patches
#define DIN    768     // 3*16*16
#define DM     384
#define KCL    16
#define NEXP   8
#define NITER  10
#define NCLS   1000

// ---------------------------------------------------------------------------
// K0: init out = cb (classifier bias), zero the merge mask
// ---------------------------------------------------------------------------
__global__ __launch_bounds__(256) void init_kernel(const float* __restrict__ cb,
                                                   float* __restrict__ out,
                                                   int* __restrict__ mask) {
    int idx = blockIdx.x * 256 + threadIdx.x;
    if (idx < NBATCH * NCLS) {
        out[idx] = cb[idx % NCLS];
    } else if (idx < NBATCH * NCLS + 256) {
        mask[idx - NBATCH * NCLS] = 0;
    }
}

// ---------------------------------------------------------------------------
// K1: patch extraction + GEMM (25088x768 @ 768x384) + bias + LayerNorm + pnsq
// 128 threads, BM=32, BK=16, micro 8x12. As k-major padded (stride 36):
// inner As reads are wave-broadcast, Ws reads 3x b128. 96 FMA per 5 LDS reads
// -> VALU-bound (fp32 floor ~94 us grid-wide).
// ---------------------------------------------------------------------------
#define BKP 16
__global__ __launch_bounds__(128) void patch_ln_kernel(
        const float* __restrict__ x, const float* __restrict__ pw,
        const float* __restrict__ pb, const float* __restrict__ lng,
        const float* __restrict__ lnb, float* __restrict__ pn,
        float* __restrict__ pnsq) {
    __shared__ float As[BKP * 36];   // [kk][row], padded stride 36
    __shared__ float Ws[BKP * DM];   // [kk][col]
    const int tid = threadIdx.x;
    const int m0  = blockIdx.x * 32;
    const int rg  = tid >> 5, cg = tid & 31;   // 4 row-groups x 32 col-groups
    // A-stage mapping: 32 loader rows x 4 k-quads
    const int lr = tid >> 2, kq = tid & 3;
    const int m  = m0 + lr;
    const int bi = m / NPTS, n = m - bi * NPTS;
    const int nh = n / 14, nwp = n - nh * 14;
    const float* xb = x + (size_t)bi * 150528 + (size_t)(nh * 16) * 224 + nwp * 16;

    float acc[8][12];
#pragma unroll
    for (int r = 0; r < 8; ++r)
#pragma unroll
        for (int j = 0; j < 12; ++j) acc[r][j] = 0.f;

    const float4* pw4 = (const float4*)pw;
    for (int kc = 0; kc < DIN; kc += BKP) {
        {   // stage A: each thread one float4 (4 consecutive k, same row)
            int k = kc + kq * 4;
            int c = k >> 8, py = (k >> 4) & 15, px = k & 15;
            float4 xv = *(const float4*)(xb + c * 50176 + py * 224 + px);
            As[(kq * 4 + 0) * 36 + lr] = xv.x;
            As[(kq * 4 + 1) * 36 + lr] = xv.y;
            As[(kq * 4 + 2) * 36 + lr] = xv.z;
            As[(kq * 4 + 3) * 36 + lr] = xv.w;
        }
        // stage W: 16x384 floats = 1536 float4, 12 per thread (contiguous)
#pragma unroll
        for (int t = 0; t < 12; ++t) {
            int s = tid + t * 128;
            ((float4*)Ws)[s] = pw4[kc * 96 + s];
        }
        __syncthreads();
#pragma unroll 4
        for (int kk = 0; kk < BKP; ++kk) {
            float a[8];
            *(float4*)&a[0] = *(const float4*)&As[kk * 36 + rg * 8];
            *(float4*)&a[4] = *(const float4*)&As[kk * 36 + rg * 8 + 4];
            float w[12];
            *(float4*)&w[0] = *(const float4*)&Ws[kk * DM + cg * 12];
            *(float4*)&w[4] = *(const float4*)&Ws[kk * DM + cg * 12 + 4];
            *(float4*)&w[8] = *(const float4*)&Ws[kk * DM + cg * 12 + 8];
#pragma unroll
            for (int r = 0; r < 8; ++r)
#pragma unroll
                for (int j = 0; j < 12; ++j) acc[r][j] += a[r] * w[j];
        }
        __syncthreads();
    }

    // epilogue: +bias, LayerNorm (two-pass), write pn and pnsq
    float gvv[12], bvv[12], pbv[12];
#pragma unroll
    for (int j4 = 0; j4 < 3; ++j4) {
        *(float4*)&pbv[j4 * 4] = *(const float4*)(pb + cg * 12 + j4 * 4);
        *(float4*)&gvv[j4 * 4] = *(const float4*)(lng + cg * 12 + j4 * 4);
        *(float4*)&bvv[j4 * 4] = *(const float4*)(lnb + cg * 12 + j4 * 4);
    }
#pragma unroll
    for (int r = 0; r < 8; ++r) {
        float vloc[12];
        float s = 0.f;
#pragma unroll
        for (int j = 0; j < 12; ++j) { vloc[j] = acc[r][j] + pbv[j]; s += vloc[j]; }
#pragma unroll
        for (int off = 16; off >= 1; off >>= 1) s += __shfl_xor(s, off);
        float mu = s * (1.0f / DM);
        float q = 0.f;
#pragma unroll
        for (int j = 0; j < 12; ++j) { float dd = vloc[j] - mu; q += dd * dd; }
#pragma unroll
        for (int off = 16; off >= 1; off >>= 1) q += __shfl_xor(q, off);
        float rstd = rsqrtf(q * (1.0f / DM) + 1e-5f);
        float ov[12];
        float ssq = 0.f;
#pragma unroll
        for (int j = 0; j < 12; ++j) {
            float p = (vloc[j] - mu) * rstd * gvv[j] + bvv[j];
            ov[j] = p; ssq += p * p;
        }
#pragma unroll
        for (int off = 16; off >= 1; off >>= 1) ssq += __shfl_xor(ssq, off);
        int mr = m0 + rg * 8 + r;
        float* dst = pn + (size_t)mr * DM + cg * 12;
        *(float4*)(dst)     = *(float4*)&ov[0];
        *(float4*)(dst + 4) = *(float4*)&ov[4];
        *(float4*)(dst + 8) = *(float4*)&ov[8];
        if (cg == 0) pnsq[mr] = ssq;
    }
}

// ---------------------------------------------------------------------------
// K2a: k-means init. centers = pn[13k], csq, cnt=0. One block per batch.
// ---------------------------------------------------------------------------
__global__ __launch_bounds__(256) void kmeans_init_kernel(
        const float* __restrict__ pn, float* __restrict__ cent,
        float* __restrict__ csq, int* __restrict__ cnt) {
    const int b = blockIdx.x, tid = threadIdx.x;
    const float* pnb = pn + (size_t)b * NPTS * DM;
    float* cb = cent + (size_t)b * KCL * DM;
    for (int i = tid; i < KCL * DM / 4; i += 256) {
        int k = i / (DM / 4), d4 = i - k * (DM / 4);
        ((float4*)cb)[i] = ((const float4*)(pnb + (size_t)(13 * k) * DM))[d4];
    }
    if (tid < 128) {
        int k = tid >> 3, sub = tid & 7;
        const float* row = pnb + (size_t)(13 * k) * DM + sub * 48;
        float ss = 0.f;
        for (int d = 0; d < 48; d += 4) {
            float4 v = *(const float4*)(row + d);
            ss += v.x * v.x + v.y * v.y + v.z * v.z + v.w * v.w;
        }
#pragma unroll
        for (int off = 4; off >= 1; off >>= 1) ss += __shfl_xor(ss, off);
        if (sub == 0) csq[b * KCL + k] = ss;
    }
    if (tid < KCL) cnt[b * KCL + tid] = 0;
}

// ---------------------------------------------------------------------------
// K2b: assignment. grid (4 tiles x 128 batches). 16 sub-lanes per point-group,
// 4 points per lane: each center LDS read feeds 16 FMA -> VALU-bound.
// ---------------------------------------------------------------------------
__global__ __launch_bounds__(256) void kmeans_assign_kernel(
        const float* __restrict__ pn, const float* __restrict__ pnsq,
        const float* __restrict__ cent, const float* __restrict__ csq,
        int* __restrict__ asn, int* __restrict__ cnt) {
    __shared__ float cs[KCL * DM];   // 24 KB
    __shared__ float cq[KCL];
    const int b = blockIdx.y, tile = blockIdx.x, tid = threadIdx.x;
    const float* cb = cent + (size_t)b * KCL * DM;
    for (int t = 0; t < 6; ++t)
        ((float4*)cs)[tid + t * 256] = ((const float4*)cb)[tid + t * 256];
    if (tid < KCL) cq[tid] = csq[b * KCL + tid];
    __syncthreads();

    const int sub = tid & 15, pg = tid >> 4;   // 16 subs x 16 point-groups
    const int n0 = tile * 64 + pg * 4;
    const float* prow[4];
#pragma unroll
    for (int pp = 0; pp < 4; ++pp) {
        int np = n0 + pp; if (np > NPTS - 1) np = NPTS - 1;
        prow[pp] = pn + ((size_t)b * NPTS + np) * DM;
    }

    float acc[KCL][4];
#pragma unroll
    for (int k = 0; k < KCL; ++k)
#pragma unroll
        for (int pp = 0; pp < 4; ++pp) acc[k][pp] = 0.f;

    for (int i = 0; i < 6; ++i) {
        const int d4 = sub + 16 * i;           // 96 chunks, stride-16 interleave
        float4 pv[4];
#pragma unroll
        for (int pp = 0; pp < 4; ++pp) pv[pp] = ((const float4*)prow[pp])[d4];
#pragma unroll
        for (int k = 0; k < KCL; ++k) {
            const float4 c = *(const float4*)&cs[k * DM + d4 * 4];
#pragma unroll
            for (int pp = 0; pp < 4; ++pp)
                acc[k][pp] += pv[pp].x * c.x + pv[pp].y * c.y +
                              pv[pp].z * c.z + pv[pp].w * c.w;
        }
    }
    // reduce over the 16 sub-lanes (low 4 lane bits)
#pragma unroll
    for (int k = 0; k < KCL; ++k)
#pragma unroll
        for (int pp = 0; pp < 4; ++pp) {
            float a = acc[k][pp];
            a += __shfl_xor(a, 1);
            a += __shfl_xor(a, 2);
            a += __shfl_xor(a, 4);
            a += __shfl_xor(a, 8);
            acc[k][pp] = a;
        }
    if (sub < 4) {                              // lane sub handles point pp=sub
        const int pp = sub, n = n0 + pp;
        if (n < NPTS) {
            const float mp = pnsq[b * NPTS + n];
            float best = (mp - 2.0f * acc[0][pp]) + cq[0];
            int bk = 0;
#pragma unroll
            for (int k = 1; k < KCL; ++k) {
                float v = (mp - 2.0f * acc[k][pp]) + cq[k];
                if (v < best) { best = v; bk = k; }   // strict < keeps first min
            }
            asn[b * NPTS + n] = bk;
            atomicAdd(&cnt[b * KCL + bk], 1);
        }
    }
}

// ---------------------------------------------------------------------------
// K2c: centers update. grid (16 k, 128 batches). Ballot-compress matching
// points into wave masks, then each thread (float2 column) sums ~12 rows.
// ---------------------------------------------------------------------------
__global__ __launch_bounds__(256) void kmeans_update_kernel(
        const float* __restrict__ pn, const int* __restrict__ asn,
        int* __restrict__ cnt, float* __restrict__ cent,
        float* __restrict__ csq) {
    __shared__ unsigned long long msk[4];
    __shared__ float red[4];
    const int b = blockIdx.y, k = blockIdx.x, tid = threadIdx.x;

    int a = -1;
    if (tid < NPTS) a = asn[b * NPTS + tid];
    unsigned long long bal = __ballot(a == k);
    if ((tid & 63) == 0) msk[tid >> 6] = bal;
    __syncthreads();

    const int c = cnt[b * KCL + k];
    float sx = 0.f, sy = 0.f;
    const float* pnb = pn + (size_t)b * NPTS * DM + 2 * tid;
    if (tid < 192) {
#pragma unroll
        for (int w = 0; w < 4; ++w) {
            unsigned long long m = msk[w];
            while (m) {
                int nn = w * 64 + (int)__builtin_ctzll(m);
                m &= m - 1;
                float2 v = *(const float2*)(pnb + (size_t)nn * DM);
                sx += v.x; sy += v.y;
            }
        }
    }
    float* cr = cent + ((size_t)b * KCL + k) * DM + 2 * tid;
    float nx = 0.f, ny = 0.f;
    if (tid < 192) {
        if (c > 0) {
            float inv = 1.0f / (float)c;
            nx = sx * inv; ny = sy * inv;
        } else {
            nx = cr[0]; ny = cr[1];
        }
        cr[0] = nx; cr[1] = ny;
    }
    float ss = nx * nx + ny * ny;
#pragma unroll
    for (int off = 32; off >= 1; off >>= 1) ss += __shfl_xor(ss, off);
    if ((tid & 63) == 0) red[tid >> 6] = ss;
    __syncthreads();
    if (tid == 0) {
        csq[b * KCL + k] = red[0] + red[1] + red[2] + red[3];
        cnt[b * KCL + k] = 0;
    }
}

// ---------------------------------------------------------------------------
// K2d: finalize clusters0 = cent + pos (in place: cent aliases c0)
// ---------------------------------------------------------------------------
__global__ __launch_bounds__(256) void kmeans_finalize_kernel(
        float* __restrict__ cent, const float* __restrict__ pos) {
    int i = blockIdx.x * 256 + threadIdx.x;          // float4 index
    int within = i % (KCL * DM / 4);
    float4 cv = ((const float4*)cent)[i];
    float4 pv = ((const float4*)pos)[within];
    cv.x += pv.x; cv.y += pv.y; cv.z += pv.z; cv.w += pv.w;
    ((float4*)cent)[i] = cv;
}

// ---------------------------------------------------------------------------
// K3: fused QKV GEMM: 3 outputs from one A-tile staging. BM=32, BN=128, BK=32.
// ---------------------------------------------------------------------------
__global__ __launch_bounds__(256) void gemm_qkv_kernel(
        const float* __restrict__ A,
        const float* __restrict__ qw, const float* __restrict__ kw,
        const float* __restrict__ vw,
        const float* __restrict__ qb, const float* __restrict__ kb,
        const float* __restrict__ vb,
        float* __restrict__ Q, float* __restrict__ K, float* __restrict__ V) {
    __shared__ float As[32 * 32];
    __shared__ float Ws[3][32 * 128];
    const int n0 = blockIdx.x * 128;
    const int m0 = blockIdx.y * 32;
    const int tid = threadIdx.x;
    const int rg = tid >> 5, cg = tid & 31;
    const int arow = tid >> 3, akg = tid & 7;
    const float* W[3] = {qw, kw, vw};

    float acc[3][4][4];
#pragma unroll
    for (int g = 0; g < 3; ++g)
#pragma unroll
        for (int r = 0; r < 4; ++r)
#pragma unroll
            for (int j = 0; j < 4; ++j) acc[g][r][j] = 0.f;

    for (int kc = 0; kc < DM; kc += 32) {
        float4 av = *(const float4*)(A + (size_t)(m0 + arow) * DM + kc + akg * 4);
        As[(akg * 4 + 0) * 32 + arow] = av.x;
        As[(akg * 4 + 1) * 32 + arow] = av.y;
        As[(akg * 4 + 2) * 32 + arow] = av.z;
        As[(akg * 4 + 3) * 32 + arow] = av.w;
#pragma unroll
        for (int g = 0; g < 3; ++g)
#pragma unroll
            for (int t = 0; t < 4; ++t) {
                int s = tid + t * 256;
                int kk = s >> 5, c4i = s & 31;
                *(float4*)&Ws[g][kk * 128 + c4i * 4] =
                    *(const float4*)(W[g] + (size_t)(kc + kk) * DM + n0 + c4i * 4);
            }
        __syncthreads();
#pragma unroll 8
        for (int kk = 0; kk < 32; ++kk) {
            float4 a = *(const float4*)&As[kk * 32 + rg * 4];
            float ar[4] = {a.x, a.y, a.z, a.w};
#pragma unroll
            for (int g = 0; g < 3; ++g) {
                float4 w = *(const float4*)&Ws[g][kk * 128 + cg * 4];
                float wr[4] = {w.x, w.y, w.z, w.w};
#pragma unroll
                for (int r = 0; r < 4; ++r)
#pragma unroll
                    for (int j = 0; j < 4; ++j) acc[g][r][j] += ar[r] * wr[j];
            }
        }
        __syncthreads();
    }
    const float* B[3] = {qb, kb, vb};
    float* O[3] = {Q, K, V};
#pragma unroll
    for (int g = 0; g < 3; ++g) {
        float4 bv = *(const float4*)(B[g] + n0 + cg * 4);
        float bvr[4] = {bv.x, bv.y, bv.z, bv.w};
#pragma unroll
        for (int r = 0; r < 4; ++r) {
            float o[4];
#pragma unroll
            for (int j = 0; j < 4; ++j) o[j] = acc[g][r][j] + bvr[j];
            *(float4*)(O[g] + (size_t)(m0 + rg * 4 + r) * DM + n0 + cg * 4) =
                *(float4*)&o[0];
        }
    }
}

// ---------------------------------------------------------------------------
// Generic fp32 GEMM: out(MxN) = A(MxK) @ W(KxN) + bias, optional exact GELU.
// ---------------------------------------------------------------------------
template <int ACT>
__global__ __launch_bounds__(256) void gemm_kernel(
        const float* __restrict__ A, const float* __restrict__ W,
        const float* __restrict__ bias, float* __restrict__ out,
        int M, int N, int Kd) {
    __shared__ float As[32 * 32];
    __shared__ float Ws[32 * 128];
    const int n0 = blockIdx.x * 128;
    const int m0 = blockIdx.y * 32;
    const int tid = threadIdx.x;
    const int rg = tid >> 5, cg = tid & 31;
    const int arow = tid >> 3, akg = tid & 7;
    float acc[4][4];
#pragma unroll
    for (int r = 0; r < 4; ++r)
#pragma unroll
        for (int j = 0; j < 4; ++j) acc[r][j] = 0.f;

    for (int kc = 0; kc < Kd; kc += 32) {
        float4 av = *(const float4*)(A + (size_t)(m0 + arow) * Kd + kc + akg * 4);
        As[(akg * 4 + 0) * 32 + arow] = av.x;
        As[(akg * 4 + 1) * 32 + arow] = av.y;
        As[(akg * 4 + 2) * 32 + arow] = av.z;
        As[(akg * 4 + 3) * 32 + arow] = av.w;
#pragma unroll
        for (int t = 0; t < 4; ++t) {
            int s = tid + t * 256;
            int kk = s >> 5, c4i = s & 31;
            *(float4*)&Ws[kk * 128 + c4i * 4] =
                *(const float4*)(W + (size_t)(kc + kk) * N + n0 + c4i * 4);
        }
        __syncthreads();
#pragma unroll 16
        for (int kk = 0; kk < 32; ++kk) {
            float4 a = *(const float4*)&As[kk * 32 + rg * 4];
            float4 w = *(const float4*)&Ws[kk * 128 + cg * 4];
            float ar[4] = {a.x, a.y, a.z, a.w};
            float wr[4] = {w.x, w.y, w.z, w.w};
#pragma unroll
            for (int r = 0; r < 4; ++r)
#pragma unroll
                for (int j = 0; j < 4; ++j) acc[r][j] += ar[r] * wr[j];
        }
        __syncthreads();
    }
    float4 bv = *(const float4*)(bias + n0 + cg * 4);
    float bvr[4] = {bv.x, bv.y, bv.z, bv.w};
#pragma unroll
    for (int r = 0; r < 4; ++r) {
        float o[4];
#pragma unroll
        for (int j = 0; j < 4; ++j) {
            float v = acc[r][j] + bvr[j];
            if (ACT == 1) v = 0.5f * v * (1.0f + erff(v * 0.70710678118654752440f));
            o[j] = v;
        }
        *(float4*)(out + (size_t)(m0 + rg * 4 + r) * N + n0 + cg * 4) = *(float4*)&o[0];
    }
}

// ---------------------------------------------------------------------------
// K4: attention + expert softmax + spectral (L @ clusters). Block = 1 batch.
// ---------------------------------------------------------------------------
__global__ __launch_bounds__(256) void attn_spectral_kernel(
        const float* __restrict__ Qg, const float* __restrict__ Kg,
        const float* __restrict__ Vg, const float* __restrict__ ew,
        const float* __restrict__ eb, float* __restrict__ c2) {
    __shared__ float Qs[KCL * 388];   // Q, later C1
    __shared__ float Ks[KCL * 388];   // K, later V
    __shared__ float ewt[NEXP * 388]; // ew transposed [e][d]
    __shared__ float Ss[KCL * 17];
    __shared__ float hws[KCL * 9];
    __shared__ float rds[NEXP];
    __shared__ float Ls[NEXP * NEXP];
    const int b = blockIdx.x, tid = threadIdx.x;
    for (int idx = tid; idx < KCL * DM; idx += 256) {
        int i = idx / DM, d = idx - i * DM;
        size_t g = (size_t)b * KCL * DM + idx;
        Qs[i * 388 + d] = Qg[g];
        Ks[i * 388 + d] = Kg[g];
    }
    for (int idx = tid; idx < DM * NEXP; idx += 256) {
        int d = idx >> 3, e = idx & 7;
        ewt[e * 388 + d] = ew[idx];
    }
    __syncthreads();
    {   // S = Q K^T / sqrt(D), softmax rows
        int i = tid >> 4, j = tid & 15;
        float acc = 0.f;
        for (int d = 0; d < DM; d += 4) {
            float4 q = *(const float4*)&Qs[i * 388 + d];
            float4 k = *(const float4*)&Ks[j * 388 + d];
            acc += q.x * k.x + q.y * k.y + q.z * k.z + q.w * k.w;
        }
        float s = acc / sqrtf((float)DM);
        float mx = s;
#pragma unroll
        for (int off = 8; off >= 1; off >>= 1) mx = fmaxf(mx, __shfl_xor(mx, off));
        float p = expf(s - mx);
        float sm = p;
#pragma unroll
        for (int off = 8; off >= 1; off >>= 1) sm += __shfl_xor(sm, off);
        Ss[i * 17 + j] = p / sm;
    }
    __syncthreads();
    for (int idx = tid; idx < KCL * DM; idx += 256) {
        int i = idx / DM, d = idx - i * DM;
        Ks[i * 388 + d] = Vg[(size_t)b * KCL * DM + idx];
    }
    __syncthreads();
    for (int idx = tid; idx < KCL * DM; idx += 256) {
        int i = idx / DM, d = idx - i * DM;
        float acc = 0.f;
#pragma unroll
        for (int j = 0; j < KCL; ++j) acc += Ss[i * 17 + j] * Ks[j * 388 + d];
        Qs[i * 388 + d] = acc;
    }
    __syncthreads();
    if (tid < 128) {
        int e = tid >> 4, i = tid & 15;
        float l = 0.f;
        for (int d4 = 0; d4 < DM / 4; ++d4) {
            float4 q = *(const float4*)&Qs[i * 388 + d4 * 4];
            float4 w = *(const float4*)&ewt[e * 388 + d4 * 4];
            l += q.x * w.x + q.y * w.y + q.z * w.z + q.w * w.w;
        }
        l += eb[e];
        float mx = l;
#pragma unroll
        for (int off = 8; off >= 1; off >>= 1) mx = fmaxf(mx, __shfl_xor(mx, off));
        float p = expf(l - mx);
        float sm = p;
#pragma unroll
        for (int off = 8; off >= 1; off >>= 1) sm += __shfl_xor(sm, off);
        float h = p / sm;
        hws[i * 9 + e] = h;
        float sd = h;
#pragma unroll
        for (int off = 8; off >= 1; off >>= 1) sd += __shfl_xor(sd, off);
        if (i == 0) rds[e] = 1.0f / sqrtf(sd);
    }
    __syncthreads();
    if (tid < 64) {
        int e = tid >> 3, f = tid & 7;
        float gsum = 0.f;
#pragma unroll
        for (int k = 0; k < KCL; ++k) gsum += hws[k * 9 + e] * hws[k * 9 + f];
        Ls[e * 8 + f] = ((e == f) ? 1.0f : 0.0f) - rds[e] * gsum;
    }
    __syncthreads();
    for (int idx = tid; idx < KCL * DM; idx += 256) {
        int i = idx / DM, d = idx - i * DM;
        float acc = 0.f;
        if (i < NEXP) {
#pragma unroll
            for (int j = 0; j < NEXP; ++j) acc += Ls[i * 8 + j] * Qs[j * 388 + d];
        }
        c2[(size_t)b * KCL * DM + idx] = acc;
    }
}

// ---------------------------------------------------------------------------
// K6: normalize rows, sim = nc @ nc^T, OR (sim>0.9) into global mask
// ---------------------------------------------------------------------------
__global__ __launch_bounds__(256) void simmask_kernel(const float* __restrict__ c4,
                                                      int* __restrict__ mask) {
    __shared__ float Cs[KCL * 388];
    __shared__ float rns[KCL];
    const int b = blockIdx.x, tid = threadIdx.x;
    for (int idx = tid; idx < KCL * DM; idx += 256) {
        int i = idx / DM, d = idx - i * DM;
        Cs[i * 388 + d] = c4[(size_t)b * KCL * DM + idx];
    }
    __syncthreads();
    {
        int i = tid >> 4, s = tid & 15;
        float ss = 0.f;
        for (int t = 0; t < 24; ++t) { float v = Cs[i * 388 + s + 16 * t]; ss += v * v; }
#pragma unroll
        for (int off = 8; off >= 1; off >>= 1) ss += __shfl_xor(ss, off);
        if (s == 0) rns[i] = 1.0f / fmaxf(sqrtf(ss), 1e-12f);
    }
    __syncthreads();
    for (int idx = tid; idx < KCL * DM; idx += 256) {
        int i = idx / DM, d = idx - i * DM;
        Cs[i * 388 + d] *= rns[i];
    }
    __syncthreads();
    {
        int i = tid >> 4, j = tid & 15;
        if (j > i) {
            float dp = 0.f;
            for (int d = 0; d < DM; d += 4) {
                float4 a = *(const float4*)&Cs[i * 388 + d];
                float4 c = *(const float4*)&Cs[j * 388 + d];
                dp += a.x * c.x + a.y * c.y + a.z * c.z + a.w * c.w;
            }
            if (dp > 0.9f) atomicOr(&mask[i * KCL + j], 1);
        }
    }
}

// ---------------------------------------------------------------------------
// K7: sequential pairwise merge + mean + feedback gate -> c5
// ---------------------------------------------------------------------------
__global__ __launch_bounds__(256) void merge_fb_kernel(
        const float* __restrict__ c4, const int* __restrict__ mask,
        const float* __restrict__ fbw, const float* __restrict__ fbb,
        const float* __restrict__ fgw, const float* __restrict__ fgb,
        float* __restrict__ c5) {
    __shared__ int   mk[256];
    __shared__ float gs[DM];
    __shared__ float wred[3];
    __shared__ float gatev;
    const int b = blockIdx.x, tid = threadIdx.x;
    mk[tid] = mask[tid];
    const bool act = tid < 192;
    const int t = tid;
    float2 v[KCL];
    if (act) {
#pragma unroll
        for (int i = 0; i < KCL; ++i)
            v[i] = *(const float2*)(c4 + (size_t)b * KCL * DM + i * DM + 2 * t);
    }
    __syncthreads();
    if (act) {
#pragma unroll
        for (int i = 0; i < KCL; ++i)
#pragma unroll
            for (int j = i + 1; j < KCL; ++j)
                if (mk[i * KCL + j]) {
                    float mx = 0.5f * (v[i].x + v[j].x);
                    float my = 0.5f * (v[i].y + v[j].y);
                    v[i].x = mx; v[i].y = my; v[j].x = mx; v[j].y = my;
                }
    }
    float2 gv = {0.f, 0.f};
    if (act) {
#pragma unroll
        for (int i = 0; i < KCL; ++i) { gv.x += v[i].x; gv.y += v[i].y; }
        gv.x *= 0.0625f; gv.y *= 0.0625f;
        gs[2 * t] = gv.x; gs[2 * t + 1] = gv.y;
    }
    float pg = act ? (gv.x * fgw[2 * t] + gv.y * fgw[2 * t + 1]) : 0.f;
#pragma unroll
    for (int off = 32; off >= 1; off >>= 1) pg += __shfl_xor(pg, off);
    if (act && (tid & 63) == 0) wred[tid >> 6] = pg;
    __syncthreads();
    if (tid == 0) {
        float d = wred[0] + wred[1] + wred[2] + fgb[0];
        gatev = 1.0f / (1.0f + expf(-d));
    }
    __syncthreads();
    if (act) {
        float fx = fbb[2 * t], fy = fbb[2 * t + 1];
        for (int j = 0; j < DM; ++j) {
            float gj = gs[j];
            const float2 w = *(const float2*)(fbw + (size_t)j * DM + 2 * t);
            fx += gj * w.x; fy += gj * w.y;
        }
        float gt = gatev;
#pragma unroll
        for (int i = 0; i < KCL; ++i) {
            float2 o = {v[i].x + fx * gt, v[i].y + fy * gt};
            *(float2*)(c5 + (size_t)b * KCL * DM + i * DM + 2 * t) = o;
        }
    }
}

// ---------------------------------------------------------------------------
// K8: classifier, split-K with fp32 atomics. out pre-initialized with cb.
// ---------------------------------------------------------------------------
__global__ __launch_bounds__(256) void cls_kernel(const float* __restrict__ A,
                                                  const float* __restrict__ Wt,
                                                  float* __restrict__ out) {
    __shared__ float As[32 * 32];
    __shared__ float Ws[32 * 128];
    const int n0 = blockIdx.x * 128;
    const int m0 = blockIdx.y * 32;
    const int k0 = blockIdx.z * 768;
    const int tid = threadIdx.x;
    const int rg = tid >> 5, cg = tid & 31;
    const int arow = tid >> 3, akg = tid & 7;
    float acc[4][4];
#pragma unroll
    for (int r = 0; r < 4; ++r)
#pragma unroll
        for (int j = 0; j < 4; ++j) acc[r][j] = 0.f;

    for (int kc = k0; kc < k0 + 768; kc += 32) {
        float4 av = *(const float4*)(A + (size_t)(m0 + arow) * (KCL * DM) + kc + akg * 4);
        As[(akg * 4 + 0) * 32 + arow] = av.x;
        As[(akg * 4 + 1) * 32 + arow] = av.y;
        As[(akg * 4 + 2) * 32 + arow] = av.z;
        As[(akg * 4 + 3) * 32 + arow] = av.w;
#pragma unroll
        for (int ti = 0; ti < 4; ++ti) {
            int s = tid + ti * 256;
            int kk = s >> 5, c4i = s & 31;
            int col = n0 + c4i * 4;
            float4 wv = make_float4(0.f, 0.f, 0.f, 0.f);
            if (col < NCLS) wv = *(const float4*)(Wt + (size_t)(kc + kk) * NCLS + col);
            *(float4*)&Ws[kk * 128 + c4i * 4] = wv;
        }
        __syncthreads();
#pragma unroll 16
        for (int kk = 0; kk < 32; ++kk) {
            float4 a = *(const float4*)&As[kk * 32 + rg * 4];
            float4 w = *(const float4*)&Ws[kk * 128 + cg * 4];
            float ar[4] = {a.x, a.y, a.z, a.w};
            float wr[4] = {w.x, w.y, w.z, w.w};
#pragma unroll
            for (int r = 0; r < 4; ++r)
#pragma unroll
                for (int j = 0; j < 4; ++j) acc[r][j] += ar[r] * wr[j];
        }
        __syncthreads();
    }
    int col = n0 + cg * 4;
    if (col < NCLS) {
#pragma unroll
        for (int r = 0; r < 4; ++r) {
            int row = m0 + rg * 4 + r;
#pragma unroll
            for (int j = 0; j < 4; ++j)
                atomicAdd(&out[(size_t)row * NCLS + col + j], acc[r][j]);
        }
    }
}

// ---------------------------------------------------------------------------
extern "C" void kernel_launch(void* const* d_in, const int* in_sizes, int n_in,
                              void* d_out, int out_size, void* d_ws, size_t ws_size,
                              hipStream_t stream) {
    const float* x   = (const float*)d_in[0];
    const float* pw  = (const float*)d_in[1];
    const float* pb  = (const float*)d_in[2];
    const float* lng = (const float*)d_in[3];
    const float* lnb = (const float*)d_in[4];
    const float* pos = (const float*)d_in[5];
    const float* qw  = (const float*)d_in[6];
    const float* qb  = (const float*)d_in[7];
    const float* kw  = (const float*)d_in[8];
    const float* kb  = (const float*)d_in[9];
    const float* vw  = (const float*)d_in[10];
    const float* vb  = (const float*)d_in[11];
    const float* ew  = (const float*)d_in[12];
    const float* eb  = (const float*)d_in[13];
    const float* nw  = (const float*)d_in[14];
    const float* nb  = (const float*)d_in[15];
    const float* m1w = (const float*)d_in[16];
    const float* m1b = (const float*)d_in[17];
    const float* m2w = (const float*)d_in[18];
    const float* m2b = (const float*)d_in[19];
    const float* fbw = (const float*)d_in[20];
    const float* fbb = (const float*)d_in[21];
    const float* fgw = (const float*)d_in[22];
    const float* fgb = (const float*)d_in[23];
    const float* cw  = (const float*)d_in[24];
    const float* cb  = (const float*)d_in[25];
    float* out = (float*)d_out;
    float* ws  = (float*)d_ws;

    // workspace layout (floats)
    float* pn_   = ws;                    // 128*196*384 = 9,633,792
    float* pnsq_ = ws + 9633792;          // 25,088
    float* c0_   = ws + 9658880;          // 786,432  (kmeans centers; then clusters0; later c5)
    float* Q_    = ws + 10445312;         // 786,432 (later c3)
    float* K_    = ws + 11231744;         // 786,432 (later h)
    float* V_    = ws + 12018176;         // 786,432 (later c4)
    float* c2_   = ws + 12804608;         // 786,432
    int*   mask_ = (int*)(ws + 13591040); // 256 ints
    float* csq_  = ws + 13591296;         // 2048
    int*   cnt_  = (int*)(ws + 13593344); // 2048 ints
    int*   asn_  = (int*)(ws + 13595392); // 25,088 ints
    float* cent_ = c0_;                   // centers evolve in place, become c0
    float* c3_ = Q_;
    float* h_  = K_;
    float* c4_ = V_;
    float* c5_ = c0_;

    init_kernel<<<501, 256, 0, stream>>>(cb, out, mask_);
    patch_ln_kernel<<<784, 128, 0, stream>>>(x, pw, pb, lng, lnb, pn_, pnsq_);

    kmeans_init_kernel<<<NBATCH, 256, 0, stream>>>(pn_, cent_, csq_, cnt_);
    for (int it = 0; it < NITER; ++it) {
        kmeans_assign_kernel<<<dim3(4, NBATCH), 256, 0, stream>>>(
            pn_, pnsq_, cent_, csq_, asn_, cnt_);
        kmeans_update_kernel<<<dim3(KCL, NBATCH), 256, 0, stream>>>(
            pn_, asn_, cnt_, cent_, csq_);
    }
    kmeans_finalize_kernel<<<768, 256, 0, stream>>>(cent_, pos);

    gemm_qkv_kernel<<<dim3(3, 64), 256, 0, stream>>>(c0_, qw, kw, vw, qb, kb, vb,
                                                     Q_, K_, V_);
    attn_spectral_kernel<<<NBATCH, 256, 0, stream>>>(Q_, K_, V_, ew, eb, c2_);
    gemm_kernel<0><<<dim3(3, 64), 256, 0, stream>>>(c2_, nw, nb, c3_, 2048, DM, DM);
    gemm_kernel<1><<<dim3(3, 64), 256, 0, stream>>>(c3_, m1w, m1b, h_, 2048, DM, DM);
    gemm_kernel<0><<<dim3(3, 64), 256, 0, stream>>>(h_, m2w, m2b, c4_, 2048, DM, DM);
    simmask_kernel<<<NBATCH, 256, 0, stream>>>(c4_, mask_);
    merge_fb_kernel<<<NBATCH, 256, 0, stream>>>(c4_, mask_, fbw, fbb, fgw, fgb, c5_);
    cls_kernel<<<dim3(8, 4, 8), 256, 0, stream>>>(c5_, cw, out);
}

// Round 4
// 1195.120 us; speedup vs baseline: 1.0409x; 1.0409x over previous
//
#include <hip/hip_runtime.h>
#include <math.h>

// Shapes (fixed by the problem)
#define NBATCH 128
#define NPTS   196     // 14*14 patches
#define DIN    768     // 3*16*16
#define DM     384
#define KCL    16
#define NEXP   8
#define NITER  10
#define NCLS   1000

// ---------------------------------------------------------------------------
// K0: init out = cb (classifier bias), zero the merge mask
// ---------------------------------------------------------------------------
__global__ __launch_bounds__(256) void init_kernel(const float* __restrict__ cb,
                                                   float* __restrict__ out,
                                                   int* __restrict__ mask) {
    int idx = blockIdx.x * 256 + threadIdx.x;
    if (idx < NBATCH * NCLS) {
        out[idx] = cb[idx % NCLS];
    } else if (idx < NBATCH * NCLS + 256) {
        mask[idx - NBATCH * NCLS] = 0;
    }
}

// ---------------------------------------------------------------------------
// K1: patch extraction + GEMM (25088x768 @ 768x384) + bias + LayerNorm + pnsq
// 256 threads (4 waves — keep TLP!), BM=64, BK=16, micro 8x12.
// FMA/LDS-byte = 96/80 = 1.2 (was 0.75 in the 4x12 version). Grid 392.
// ---------------------------------------------------------------------------
#define BKP 16
__global__ __launch_bounds__(256) void patch_ln_kernel(
        const float* __restrict__ x, const float* __restrict__ pw,
        const float* __restrict__ pb, const float* __restrict__ lng,
        const float* __restrict__ lnb, float* __restrict__ pn,
        float* __restrict__ pnsq) {
    __shared__ float As[BKP * 68];   // [kk][row], 64 rows + 4 pad
    __shared__ float Ws[BKP * DM];   // [kk][col]
    const int tid = threadIdx.x;
    const int m0  = blockIdx.x * 64;
    const int rg  = tid >> 5, cg = tid & 31;   // 8 row-groups x 32 col-groups
    // A-stage mapping: 64 loader rows x 4 k-quads
    const int lr = tid >> 2, kq = tid & 3;
    const int m  = m0 + lr;
    const int bi = m / NPTS, n = m - bi * NPTS;
    const int nh = n / 14, nwp = n - nh * 14;
    const float* xb = x + (size_t)bi * 150528 + (size_t)(nh * 16) * 224 + nwp * 16;

    float acc[8][12];
#pragma unroll
    for (int r = 0; r < 8; ++r)
#pragma unroll
        for (int j = 0; j < 12; ++j) acc[r][j] = 0.f;

    const float4* pw4 = (const float4*)pw;
    for (int kc = 0; kc < DIN; kc += BKP) {
        {   // stage A: each thread one float4 (4 consecutive k, same row)
            int k = kc + kq * 4;
            int c = k >> 8, py = (k >> 4) & 15, px = k & 15;
            float4 xv = *(const float4*)(xb + c * 50176 + py * 224 + px);
            As[(kq * 4 + 0) * 68 + lr] = xv.x;
            As[(kq * 4 + 1) * 68 + lr] = xv.y;
            As[(kq * 4 + 2) * 68 + lr] = xv.z;
            As[(kq * 4 + 3) * 68 + lr] = xv.w;
        }
        // stage W: 16x384 floats = 1536 float4, 6 per thread (contiguous)
#pragma unroll
        for (int t = 0; t < 6; ++t) {
            int s = tid + t * 256;
            ((float4*)Ws)[s] = pw4[kc * 96 + s];
        }
        __syncthreads();
#pragma unroll 2
        for (int kk = 0; kk < BKP; ++kk) {
            float a[8];
            *(float4*)&a[0] = *(const float4*)&As[kk * 68 + rg * 8];
            *(float4*)&a[4] = *(const float4*)&As[kk * 68 + rg * 8 + 4];
            float w[12];
            *(float4*)&w[0] = *(const float4*)&Ws[kk * DM + cg * 12];
            *(float4*)&w[4] = *(const float4*)&Ws[kk * DM + cg * 12 + 4];
            *(float4*)&w[8] = *(const float4*)&Ws[kk * DM + cg * 12 + 8];
#pragma unroll
            for (int r = 0; r < 8; ++r)
#pragma unroll
                for (int j = 0; j < 12; ++j) acc[r][j] += a[r] * w[j];
        }
        __syncthreads();
    }

    // epilogue: +bias, LayerNorm (two-pass), write pn and pnsq
    float gvv[12], bvv[12], pbv[12];
#pragma unroll
    for (int j4 = 0; j4 < 3; ++j4) {
        *(float4*)&pbv[j4 * 4] = *(const float4*)(pb + cg * 12 + j4 * 4);
        *(float4*)&gvv[j4 * 4] = *(const float4*)(lng + cg * 12 + j4 * 4);
        *(float4*)&bvv[j4 * 4] = *(const float4*)(lnb + cg * 12 + j4 * 4);
    }
#pragma unroll
    for (int r = 0; r < 8; ++r) {
        float vloc[12];
        float s = 0.f;
#pragma unroll
        for (int j = 0; j < 12; ++j) { vloc[j] = acc[r][j] + pbv[j]; s += vloc[j]; }
#pragma unroll
        for (int off = 16; off >= 1; off >>= 1) s += __shfl_xor(s, off);
        float mu = s * (1.0f / DM);
        float q = 0.f;
#pragma unroll
        for (int j = 0; j < 12; ++j) { float dd = vloc[j] - mu; q += dd * dd; }
#pragma unroll
        for (int off = 16; off >= 1; off >>= 1) q += __shfl_xor(q, off);
        float rstd = rsqrtf(q * (1.0f / DM) + 1e-5f);
        float ov[12];
        float ssq = 0.f;
#pragma unroll
        for (int j = 0; j < 12; ++j) {
            float p = (vloc[j] - mu) * rstd * gvv[j] + bvv[j];
            ov[j] = p; ssq += p * p;
        }
#pragma unroll
        for (int off = 16; off >= 1; off >>= 1) ssq += __shfl_xor(ssq, off);
        int mr = m0 + rg * 8 + r;
        float* dst = pn + (size_t)mr * DM + cg * 12;
        *(float4*)(dst)     = *(float4*)&ov[0];
        *(float4*)(dst + 4) = *(float4*)&ov[4];
        *(float4*)(dst + 8) = *(float4*)&ov[8];
        if (cg == 0) pnsq[mr] = ssq;
    }
}

// ---------------------------------------------------------------------------
// K2a: k-means init. centers = pn[13k], csq. One block per batch.
// ---------------------------------------------------------------------------
__global__ __launch_bounds__(256) void kmeans_init_kernel(
        const float* __restrict__ pn, float* __restrict__ cent,
        float* __restrict__ csq) {
    const int b = blockIdx.x, tid = threadIdx.x;
    const float* pnb = pn + (size_t)b * NPTS * DM;
    float* cb = cent + (size_t)b * KCL * DM;
    for (int i = tid; i < KCL * DM / 4; i += 256) {
        int k = i / (DM / 4), d4 = i - k * (DM / 4);
        ((float4*)cb)[i] = ((const float4*)(pnb + (size_t)(13 * k) * DM))[d4];
    }
    if (tid < 128) {
        int k = tid >> 3, sub = tid & 7;
        const float* row = pnb + (size_t)(13 * k) * DM + sub * 48;
        float ss = 0.f;
        for (int d = 0; d < 48; d += 4) {
            float4 v = *(const float4*)(row + d);
            ss += v.x * v.x + v.y * v.y + v.z * v.z + v.w * v.w;
        }
#pragma unroll
        for (int off = 4; off >= 1; off >>= 1) ss += __shfl_xor(ss, off);
        if (sub == 0) csq[b * KCL + k] = ss;
    }
}

// ---------------------------------------------------------------------------
// K2b: one k-means iteration, fused. grid (4 tiles x 128 batches).
// Phase 1: assignment (proven sub-lane pattern, 4 pts/lane) -> asn in LDS.
// Phase 2: deterministic per-(k,colgroup)-owner partial sums over the tile
// (rows re-read from L1/L2-hot global), written to gsums[b][tile][k][:].
// No float atomics anywhere -> bit-deterministic.
// ---------------------------------------------------------------------------
__global__ __launch_bounds__(256) void kmeans_iter_kernel(
        const float* __restrict__ pn, const float* __restrict__ pnsq,
        const float* __restrict__ cent, const float* __restrict__ csq,
        float* __restrict__ gsums, int* __restrict__ gcnt) {
    __shared__ float cs[KCL * DM];   // 24 KB
    __shared__ float cq[KCL];
    __shared__ int   asn_s[64];
    __shared__ int   tcnt[KCL];
    const int b = blockIdx.y, tile = blockIdx.x, tid = threadIdx.x;
    const float* cb = cent + (size_t)b * KCL * DM;
    for (int t = 0; t < 6; ++t)
        ((float4*)cs)[tid + t * 256] = ((const float4*)cb)[tid + t * 256];
    if (tid < KCL) { cq[tid] = csq[b * KCL + tid]; tcnt[tid] = 0; }
    __syncthreads();

    // ---- phase 1: assignment ----
    const int sub = tid & 15, pg = tid >> 4;   // 16 subs x 16 point-groups
    const int n0 = tile * 64 + pg * 4;
    const float* prow[4];
#pragma unroll
    for (int pp = 0; pp < 4; ++pp) {
        int np = n0 + pp; if (np > NPTS - 1) np = NPTS - 1;
        prow[pp] = pn + ((size_t)b * NPTS + np) * DM;
    }
    float acc[KCL][4];
#pragma unroll
    for (int k = 0; k < KCL; ++k)
#pragma unroll
        for (int pp = 0; pp < 4; ++pp) acc[k][pp] = 0.f;
    for (int i = 0; i < 6; ++i) {
        const int d4 = sub + 16 * i;
        float4 pv[4];
#pragma unroll
        for (int pp = 0; pp < 4; ++pp) pv[pp] = ((const float4*)prow[pp])[d4];
#pragma unroll
        for (int k = 0; k < KCL; ++k) {
            const float4 c = *(const float4*)&cs[k * DM + d4 * 4];
#pragma unroll
            for (int pp = 0; pp < 4; ++pp)
                acc[k][pp] += pv[pp].x * c.x + pv[pp].y * c.y +
                              pv[pp].z * c.z + pv[pp].w * c.w;
        }
    }
#pragma unroll
    for (int k = 0; k < KCL; ++k)
#pragma unroll
        for (int pp = 0; pp < 4; ++pp) {
            float a = acc[k][pp];
            a += __shfl_xor(a, 1);
            a += __shfl_xor(a, 2);
            a += __shfl_xor(a, 4);
            a += __shfl_xor(a, 8);
            acc[k][pp] = a;
        }
    if (sub < 4) {                              // lane sub handles point pp=sub
        const int pp = sub, n = n0 + pp;
        if (n < NPTS) {
            const float mp = pnsq[b * NPTS + n];
            float best = (mp - 2.0f * acc[0][pp]) + cq[0];
            int bk = 0;
#pragma unroll
            for (int k = 1; k < KCL; ++k) {
                float v = (mp - 2.0f * acc[k][pp]) + cq[k];
                if (v < best) { best = v; bk = k; }   // strict < keeps first min
            }
            asn_s[pg * 4 + pp] = bk;
            atomicAdd(&tcnt[bk], 1);            // int atomic: deterministic value
        } else {
            asn_s[pg * 4 + pp] = -1;
        }
    }
    __syncthreads();

    // ---- phase 2: per-tile partial sums, thread = (k, colgroup of 32) ----
    if (tid < 192) {
        const int k = tid / 12, cgp = tid - k * 12;
        const float* base = pn + ((size_t)b * NPTS + tile * 64) * DM + cgp * 32;
        float4 s[8];
#pragma unroll
        for (int q = 0; q < 8; ++q) s[q] = make_float4(0.f, 0.f, 0.f, 0.f);
        for (int nn = 0; nn < 64; ++nn) {       // ascending order: deterministic
            if (asn_s[nn] == k) {
                const float4* r = (const float4*)(base + (size_t)nn * DM);
#pragma unroll
                for (int q = 0; q < 8; ++q) {
                    float4 v = r[q];
                    s[q].x += v.x; s[q].y += v.y; s[q].z += v.z; s[q].w += v.w;
                }
            }
        }
        float4* dst = (float4*)(gsums + (((size_t)(b * 4 + tile) * KCL + k) * DM)
                                + cgp * 32);
#pragma unroll
        for (int q = 0; q < 8; ++q) dst[q] = s[q];
    }
    if (tid < KCL) gcnt[(b * 4 + tile) * KCL + tid] = tcnt[tid];
}

// ---------------------------------------------------------------------------
// K2c: reduce 4 tiles (fixed order), divide, handle empty clusters, csq.
// One block per batch.
// ---------------------------------------------------------------------------
__global__ __launch_bounds__(256) void kmeans_newcent_kernel(
        const float* __restrict__ gsums, const int* __restrict__ gcnt,
        float* __restrict__ cent, float* __restrict__ csq) {
    __shared__ float centS[KCL * DM];  // 24 KB
    __shared__ int   cntS[KCL];
    const int b = blockIdx.x, tid = threadIdx.x;
    if (tid < KCL) {
        int c = 0;
#pragma unroll
        for (int t = 0; t < 4; ++t) c += gcnt[(b * 4 + t) * KCL + tid];
        cntS[tid] = c;
    }
    __syncthreads();
    const float4* G = (const float4*)gsums;
    float4* cb4 = (float4*)(cent + (size_t)b * KCL * DM);
    for (int i = tid; i < KCL * DM / 4; i += 256) {
        int k = i / 96;
        float4 s = G[(size_t)(b * 4 + 0) * 1536 + i];
#pragma unroll
        for (int t = 1; t < 4; ++t) {
            float4 v = G[(size_t)(b * 4 + t) * 1536 + i];
            s.x += v.x; s.y += v.y; s.z += v.z; s.w += v.w;
        }
        int c = cntS[k];
        float4 o;
        if (c > 0) {
            float inv = 1.0f / (float)c;
            o = make_float4(s.x * inv, s.y * inv, s.z * inv, s.w * inv);
        } else {
            o = cb4[i];
        }
        ((float4*)centS)[i] = o;
        cb4[i] = o;
    }
    __syncthreads();
    {   // csq of the new centers
        int k = tid >> 4, su = tid & 15;
        float ss = 0.f;
        for (int t = 0; t < 24; ++t) { float v = centS[k * DM + su + 16 * t]; ss += v * v; }
#pragma unroll
        for (int off = 8; off >= 1; off >>= 1) ss += __shfl_xor(ss, off);
        if (su == 0) csq[b * KCL + k] = ss;
    }
}

// ---------------------------------------------------------------------------
// K2d: finalize clusters0 = cent + pos (in place: cent aliases c0)
// ---------------------------------------------------------------------------
__global__ __launch_bounds__(256) void kmeans_finalize_kernel(
        float* __restrict__ cent, const float* __restrict__ pos) {
    int i = blockIdx.x * 256 + threadIdx.x;          // float4 index
    int within = i % (KCL * DM / 4);
    float4 cv = ((const float4*)cent)[i];
    float4 pv = ((const float4*)pos)[within];
    cv.x += pv.x; cv.y += pv.y; cv.z += pv.z; cv.w += pv.w;
    ((float4*)cent)[i] = cv;
}

// ---------------------------------------------------------------------------
// K3: fused QKV GEMM: 3 outputs from one A-tile staging. BM=32, BN=128, BK=32.
// ---------------------------------------------------------------------------
__global__ __launch_bounds__(256) void gemm_qkv_kernel(
        const float* __restrict__ A,
        const float* __restrict__ qw, const float* __restrict__ kw,
        const float* __restrict__ vw,
        const float* __restrict__ qb, const float* __restrict__ kb,
        const float* __restrict__ vb,
        float* __restrict__ Q, float* __restrict__ K, float* __restrict__ V) {
    __shared__ float As[32 * 32];
    __shared__ float Ws[3][32 * 128];
    const int n0 = blockIdx.x * 128;
    const int m0 = blockIdx.y * 32;
    const int tid = threadIdx.x;
    const int rg = tid >> 5, cg = tid & 31;
    const int arow = tid >> 3, akg = tid & 7;
    const float* W[3] = {qw, kw, vw};

    float acc[3][4][4];
#pragma unroll
    for (int g = 0; g < 3; ++g)
#pragma unroll
        for (int r = 0; r < 4; ++r)
#pragma unroll
            for (int j = 0; j < 4; ++j) acc[g][r][j] = 0.f;

    for (int kc = 0; kc < DM; kc += 32) {
        float4 av = *(const float4*)(A + (size_t)(m0 + arow) * DM + kc + akg * 4);
        As[(akg * 4 + 0) * 32 + arow] = av.x;
        As[(akg * 4 + 1) * 32 + arow] = av.y;
        As[(akg * 4 + 2) * 32 + arow] = av.z;
        As[(akg * 4 + 3) * 32 + arow] = av.w;
#pragma unroll
        for (int g = 0; g < 3; ++g)
#pragma unroll
            for (int t = 0; t < 4; ++t) {
                int s = tid + t * 256;
                int kk = s >> 5, c4i = s & 31;
                *(float4*)&Ws[g][kk * 128 + c4i * 4] =
                    *(const float4*)(W[g] + (size_t)(kc + kk) * DM + n0 + c4i * 4);
            }
        __syncthreads();
#pragma unroll 8
        for (int kk = 0; kk < 32; ++kk) {
            float4 a = *(const float4*)&As[kk * 32 + rg * 4];
            float ar[4] = {a.x, a.y, a.z, a.w};
#pragma unroll
            for (int g = 0; g < 3; ++g) {
                float4 w = *(const float4*)&Ws[g][kk * 128 + cg * 4];
                float wr[4] = {w.x, w.y, w.z, w.w};
#pragma unroll
                for (int r = 0; r < 4; ++r)
#pragma unroll
                    for (int j = 0; j < 4; ++j) acc[g][r][j] += ar[r] * wr[j];
            }
        }
        __syncthreads();
    }
    const float* B[3] = {qb, kb, vb};
    float* O[3] = {Q, K, V};
#pragma unroll
    for (int g = 0; g < 3; ++g) {
        float4 bv = *(const float4*)(B[g] + n0 + cg * 4);
        float bvr[4] = {bv.x, bv.y, bv.z, bv.w};
#pragma unroll
        for (int r = 0; r < 4; ++r) {
            float o[4];
#pragma unroll
            for (int j = 0; j < 4; ++j) o[j] = acc[g][r][j] + bvr[j];
            *(float4*)(O[g] + (size_t)(m0 + rg * 4 + r) * DM + n0 + cg * 4) =
                *(float4*)&o[0];
        }
    }
}

// ---------------------------------------------------------------------------
// Generic fp32 GEMM: out(MxN) = A(MxK) @ W(KxN) + bias, optional exact GELU.
// ---------------------------------------------------------------------------
template <int ACT>
__global__ __launch_bounds__(256) void gemm_kernel(
        const float* __restrict__ A, const float* __restrict__ W,
        const float* __restrict__ bias, float* __restrict__ out,
        int M, int N, int Kd) {
    __shared__ float As[32 * 32];
    __shared__ float Ws[32 * 128];
    const int n0 = blockIdx.x * 128;
    const int m0 = blockIdx.y * 32;
    const int tid = threadIdx.x;
    const int rg = tid >> 5, cg = tid & 31;
    const int arow = tid >> 3, akg = tid & 7;
    float acc[4][4];
#pragma unroll
    for (int r = 0; r < 4; ++r)
#pragma unroll
        for (int j = 0; j < 4; ++j) acc[r][j] = 0.f;

    for (int kc = 0; kc < Kd; kc += 32) {
        float4 av = *(const float4*)(A + (size_t)(m0 + arow) * Kd + kc + akg * 4);
        As[(akg * 4 + 0) * 32 + arow] = av.x;
        As[(akg * 4 + 1) * 32 + arow] = av.y;
        As[(akg * 4 + 2) * 32 + arow] = av.z;
        As[(akg * 4 + 3) * 32 + arow] = av.w;
#pragma unroll
        for (int t = 0; t < 4; ++t) {
            int s = tid + t * 256;
            int kk = s >> 5, c4i = s & 31;
            *(float4*)&Ws[kk * 128 + c4i * 4] =
                *(const float4*)(W + (size_t)(kc + kk) * N + n0 + c4i * 4);
        }
        __syncthreads();
#pragma unroll 16
        for (int kk = 0; kk < 32; ++kk) {
            float4 a = *(const float4*)&As[kk * 32 + rg * 4];
            float4 w = *(const float4*)&Ws[kk * 128 + cg * 4];
            float ar[4] = {a.x, a.y, a.z, a.w};
            float wr[4] = {w.x, w.y, w.z, w.w};
#pragma unroll
            for (int r = 0; r < 4; ++r)
#pragma unroll
                for (int j = 0; j < 4; ++j) acc[r][j] += ar[r] * wr[j];
        }
        __syncthreads();
    }
    float4 bv = *(const float4*)(bias + n0 + cg * 4);
    float bvr[4] = {bv.x, bv.y, bv.z, bv.w};
#pragma unroll
    for (int r = 0; r < 4; ++r) {
        float o[4];
#pragma unroll
        for (int j = 0; j < 4; ++j) {
            float v = acc[r][j] + bvr[j];
            if (ACT == 1) v = 0.5f * v * (1.0f + erff(v * 0.70710678118654752440f));
            o[j] = v;
        }
        *(float4*)(out + (size_t)(m0 + rg * 4 + r) * N + n0 + cg * 4) = *(float4*)&o[0];
    }
}

// ---------------------------------------------------------------------------
// K4: attention + expert softmax + spectral (L @ clusters). Block = 1 batch.
// ---------------------------------------------------------------------------
__global__ __launch_bounds__(256) void attn_spectral_kernel(
        const float* __restrict__ Qg, const float* __restrict__ Kg,
        const float* __restrict__ Vg, const float* __restrict__ ew,
        const float* __restrict__ eb, float* __restrict__ c2) {
    __shared__ float Qs[KCL * 388];   // Q, later C1
    __shared__ float Ks[KCL * 388];   // K, later V
    __shared__ float ewt[NEXP * 388]; // ew transposed [e][d]
    __shared__ float Ss[KCL * 17];
    __shared__ float hws[KCL * 9];
    __shared__ float rds[NEXP];
    __shared__ float Ls[NEXP * NEXP];
    const int b = blockIdx.x, tid = threadIdx.x;
    for (int idx = tid; idx < KCL * DM; idx += 256) {
        int i = idx / DM, d = idx - i * DM;
        size_t g = (size_t)b * KCL * DM + idx;
        Qs[i * 388 + d] = Qg[g];
        Ks[i * 388 + d] = Kg[g];
    }
    for (int idx = tid; idx < DM * NEXP; idx += 256) {
        int d = idx >> 3, e = idx & 7;
        ewt[e * 388 + d] = ew[idx];
    }
    __syncthreads();
    {   // S = Q K^T / sqrt(D), softmax rows
        int i = tid >> 4, j = tid & 15;
        float acc = 0.f;
        for (int d = 0; d < DM; d += 4) {
            float4 q = *(const float4*)&Qs[i * 388 + d];
            float4 k = *(const float4*)&Ks[j * 388 + d];
            acc += q.x * k.x + q.y * k.y + q.z * k.z + q.w * k.w;
        }
        float s = acc / sqrtf((float)DM);
        float mx = s;
#pragma unroll
        for (int off = 8; off >= 1; off >>= 1) mx = fmaxf(mx, __shfl_xor(mx, off));
        float p = expf(s - mx);
        float sm = p;
#pragma unroll
        for (int off = 8; off >= 1; off >>= 1) sm += __shfl_xor(sm, off);
        Ss[i * 17 + j] = p / sm;
    }
    __syncthreads();
    for (int idx = tid; idx < KCL * DM; idx += 256) {
        int i = idx / DM, d = idx - i * DM;
        Ks[i * 388 + d] = Vg[(size_t)b * KCL * DM + idx];
    }
    __syncthreads();
    for (int idx = tid; idx < KCL * DM; idx += 256) {
        int i = idx / DM, d = idx - i * DM;
        float acc = 0.f;
#pragma unroll
        for (int j = 0; j < KCL; ++j) acc += Ss[i * 17 + j] * Ks[j * 388 + d];
        Qs[i * 388 + d] = acc;
    }
    __syncthreads();
    if (tid < 128) {
        int e = tid >> 4, i = tid & 15;
        float l = 0.f;
        for (int d4 = 0; d4 < DM / 4; ++d4) {
            float4 q = *(const float4*)&Qs[i * 388 + d4 * 4];
            float4 w = *(const float4*)&ewt[e * 388 + d4 * 4];
            l += q.x * w.x + q.y * w.y + q.z * w.z + q.w * w.w;
        }
        l += eb[e];
        float mx = l;
#pragma unroll
        for (int off = 8; off >= 1; off >>= 1) mx = fmaxf(mx, __shfl_xor(mx, off));
        float p = expf(l - mx);
        float sm = p;
#pragma unroll
        for (int off = 8; off >= 1; off >>= 1) sm += __shfl_xor(sm, off);
        float h = p / sm;
        hws[i * 9 + e] = h;
        float sd = h;
#pragma unroll
        for (int off = 8; off >= 1; off >>= 1) sd += __shfl_xor(sd, off);
        if (i == 0) rds[e] = 1.0f / sqrtf(sd);
    }
    __syncthreads();
    if (tid < 64) {
        int e = tid >> 3, f = tid & 7;
        float gsum = 0.f;
#pragma unroll
        for (int k = 0; k < KCL; ++k) gsum += hws[k * 9 + e] * hws[k * 9 + f];
        Ls[e * 8 + f] = ((e == f) ? 1.0f : 0.0f) - rds[e] * gsum;
    }
    __syncthreads();
    for (int idx = tid; idx < KCL * DM; idx += 256) {
        int i = idx / DM, d = idx - i * DM;
        float acc = 0.f;
        if (i < NEXP) {
#pragma unroll
            for (int j = 0; j < NEXP; ++j) acc += Ls[i * 8 + j] * Qs[j * 388 + d];
        }
        c2[(size_t)b * KCL * DM + idx] = acc;
    }
}

// ---------------------------------------------------------------------------
// K6: normalize rows, sim = nc @ nc^T, OR (sim>0.9) into global mask
// ---------------------------------------------------------------------------
__global__ __launch_bounds__(256) void simmask_kernel(const float* __restrict__ c4,
                                                      int* __restrict__ mask) {
    __shared__ float Cs[KCL * 388];
    __shared__ float rns[KCL];
    const int b = blockIdx.x, tid = threadIdx.x;
    for (int idx = tid; idx < KCL * DM; idx += 256) {
        int i = idx / DM, d = idx - i * DM;
        Cs[i * 388 + d] = c4[(size_t)b * KCL * DM + idx];
    }
    __syncthreads();
    {
        int i = tid >> 4, s = tid & 15;
        float ss = 0.f;
        for (int t = 0; t < 24; ++t) { float v = Cs[i * 388 + s + 16 * t]; ss += v * v; }
#pragma unroll
        for (int off = 8; off >= 1; off >>= 1) ss += __shfl_xor(ss, off);
        if (s == 0) rns[i] = 1.0f / fmaxf(sqrtf(ss), 1e-12f);
    }
    __syncthreads();
    for (int idx = tid; idx < KCL * DM; idx += 256) {
        int i = idx / DM, d = idx - i * DM;
        Cs[i * 388 + d] *= rns[i];
    }
    __syncthreads();
    {
        int i = tid >> 4, j = tid & 15;
        if (j > i) {
            float dp = 0.f;
            for (int d = 0; d < DM; d += 4) {
                float4 a = *(const float4*)&Cs[i * 388 + d];
                float4 c = *(const float4*)&Cs[j * 388 + d];
                dp += a.x * c.x + a.y * c.y + a.z * c.z + a.w * c.w;
            }
            if (dp > 0.9f) atomicOr(&mask[i * KCL + j], 1);
        }
    }
}

// ---------------------------------------------------------------------------
// K7: sequential pairwise merge + mean + feedback gate -> c5
// ---------------------------------------------------------------------------
__global__ __launch_bounds__(256) void merge_fb_kernel(
        const float* __restrict__ c4, const int* __restrict__ mask,
        const float* __restrict__ fbw, const float* __restrict__ fbb,
        const float* __restrict__ fgw, const float* __restrict__ fgb,
        float* __restrict__ c5) {
    __shared__ int   mk[256];
    __shared__ float gs[DM];
    __shared__ float wred[3];
    __shared__ float gatev;
    const int b = blockIdx.x, tid = threadIdx.x;
    mk[tid] = mask[tid];
    const bool act = tid < 192;
    const int t = tid;
    float2 v[KCL];
    if (act) {
#pragma unroll
        for (int i = 0; i < KCL; ++i)
            v[i] = *(const float2*)(c4 + (size_t)b * KCL * DM + i * DM + 2 * t);
    }
    __syncthreads();
    if (act) {
#pragma unroll
        for (int i = 0; i < KCL; ++i)
#pragma unroll
            for (int j = i + 1; j < KCL; ++j)
                if (mk[i * KCL + j]) {
                    float mx = 0.5f * (v[i].x + v[j].x);
                    float my = 0.5f * (v[i].y + v[j].y);
                    v[i].x = mx; v[i].y = my; v[j].x = mx; v[j].y = my;
                }
    }
    float2 gv = {0.f, 0.f};
    if (act) {
#pragma unroll
        for (int i = 0; i < KCL; ++i) { gv.x += v[i].x; gv.y += v[i].y; }
        gv.x *= 0.0625f; gv.y *= 0.0625f;
        gs[2 * t] = gv.x; gs[2 * t + 1] = gv.y;
    }
    float pg = act ? (gv.x * fgw[2 * t] + gv.y * fgw[2 * t + 1]) : 0.f;
#pragma unroll
    for (int off = 32; off >= 1; off >>= 1) pg += __shfl_xor(pg, off);
    if (act && (tid & 63) == 0) wred[tid >> 6] = pg;
    __syncthreads();
    if (tid == 0) {
        float d = wred[0] + wred[1] + wred[2] + fgb[0];
        gatev = 1.0f / (1.0f + expf(-d));
    }
    __syncthreads();
    if (act) {
        float fx = fbb[2 * t], fy = fbb[2 * t + 1];
        for (int j = 0; j < DM; ++j) {
            float gj = gs[j];
            const float2 w = *(const float2*)(fbw + (size_t)j * DM + 2 * t);
            fx += gj * w.x; fy += gj * w.y;
        }
        float gt = gatev;
#pragma unroll
        for (int i = 0; i < KCL; ++i) {
            float2 o = {v[i].x + fx * gt, v[i].y + fy * gt};
            *(float2*)(c5 + (size_t)b * KCL * DM + i * DM + 2 * t) = o;
        }
    }
}

// ---------------------------------------------------------------------------
// K8: classifier, split-K with fp32 atomics. out pre-initialized with cb.
// ---------------------------------------------------------------------------
__global__ __launch_bounds__(256) void cls_kernel(const float* __restrict__ A,
                                                  const float* __restrict__ Wt,
                                                  float* __restrict__ out) {
    __shared__ float As[32 * 32];
    __shared__ float Ws[32 * 128];
    const int n0 = blockIdx.x * 128;
    const int m0 = blockIdx.y * 32;
    const int k0 = blockIdx.z * 768;
    const int tid = threadIdx.x;
    const int rg = tid >> 5, cg = tid & 31;
    const int arow = tid >> 3, akg = tid & 7;
    float acc[4][4];
#pragma unroll
    for (int r = 0; r < 4; ++r)
#pragma unroll
        for (int j = 0; j < 4; ++j) acc[r][j] = 0.f;

    for (int kc = k0; kc < k0 + 768; kc += 32) {
        float4 av = *(const float4*)(A + (size_t)(m0 + arow) * (KCL * DM) + kc + akg * 4);
        As[(akg * 4 + 0) * 32 + arow] = av.x;
        As[(akg * 4 + 1) * 32 + arow] = av.y;
        As[(akg * 4 + 2) * 32 + arow] = av.z;
        As[(akg * 4 + 3) * 32 + arow] = av.w;
#pragma unroll
        for (int ti = 0; ti < 4; ++ti) {
            int s = tid + ti * 256;
            int kk = s >> 5, c4i = s & 31;
            int col = n0 + c4i * 4;
            float4 wv = make_float4(0.f, 0.f, 0.f, 0.f);
            if (col < NCLS) wv = *(const float4*)(Wt + (size_t)(kc + kk) * NCLS + col);
            *(float4*)&Ws[kk * 128 + c4i * 4] = wv;
        }
        __syncthreads();
#pragma unroll 16
        for (int kk = 0; kk < 32; ++kk) {
            float4 a = *(const float4*)&As[kk * 32 + rg * 4];
            float4 w = *(const float4*)&Ws[kk * 128 + cg * 4];
            float ar[4] = {a.x, a.y, a.z, a.w};
            float wr[4] = {w.x, w.y, w.z, w.w};
#pragma unroll
            for (int r = 0; r < 4; ++r)
#pragma unroll
                for (int j = 0; j < 4; ++j) acc[r][j] += ar[r] * wr[j];
        }
        __syncthreads();
    }
    int col = n0 + cg * 4;
    if (col < NCLS) {
#pragma unroll
        for (int r = 0; r < 4; ++r) {
            int row = m0 + rg * 4 + r;
#pragma unroll
            for (int j = 0; j < 4; ++j)
                atomicAdd(&out[(size_t)row * NCLS + col + j], acc[r][j]);
        }
    }
}

// ---------------------------------------------------------------------------
extern "C" void kernel_launch(void* const* d_in, const int* in_sizes, int n_in,
                              void* d_out, int out_size, void* d_ws, size_t ws_size,
                              hipStream_t stream) {
    const float* x   = (const float*)d_in[0];
    const float* pw  = (const float*)d_in[1];
    const float* pb  = (const float*)d_in[2];
    const float* lng = (const float*)d_in[3];
    const float* lnb = (const float*)d_in[4];
    const float* pos = (const float*)d_in[5];
    const float* qw  = (const float*)d_in[6];
    const float* qb  = (const float*)d_in[7];
    const float* kw  = (const float*)d_in[8];
    const float* kb  = (const float*)d_in[9];
    const float* vw  = (const float*)d_in[10];
    const float* vb  = (const float*)d_in[11];
    const float* ew  = (const float*)d_in[12];
    const float* eb  = (const float*)d_in[13];
    const float* nw  = (const float*)d_in[14];
    const float* nb  = (const float*)d_in[15];
    const float* m1w = (const float*)d_in[16];
    const float* m1b = (const float*)d_in[17];
    const float* m2w = (const float*)d_in[18];
    const float* m2b = (const float*)d_in[19];
    const float* fbw = (const float*)d_in[20];
    const float* fbb = (const float*)d_in[21];
    const float* fgw = (const float*)d_in[22];
    const float* fgb = (const float*)d_in[23];
    const float* cw  = (const float*)d_in[24];
    const float* cb  = (const float*)d_in[25];
    float* out = (float*)d_out;
    float* ws  = (float*)d_ws;

    // workspace layout (floats)
    float* pn_   = ws;                    // 128*196*384 = 9,633,792
    float* pnsq_ = ws + 9633792;          // 25,088
    float* c0_   = ws + 9658880;          // 786,432  (kmeans centers; then clusters0; later c5)
    float* Q_    = ws + 10445312;         // 786,432 (later c3)
    float* K_    = ws + 11231744;         // 786,432 (later h)
    float* V_    = ws + 12018176;         // 786,432 (later c4)
    float* c2_   = ws + 12804608;         // 786,432
    int*   mask_ = (int*)(ws + 13591040); // 256 ints
    float* csq_  = ws + 13591296;         // 2048
    int*   gcnt_ = (int*)(ws + 13595392); // 8192 ints (old asn region)
    float* gsums_= Q_;                    // 128*4*16*384 = 3,145,728 floats
                                          //  = spans Q_..c2_ (dead during kmeans)
    float* cent_ = c0_;                   // centers evolve in place, become c0
    float* c3_ = Q_;
    float* h_  = K_;
    float* c4_ = V_;
    float* c5_ = c0_;

    init_kernel<<<501, 256, 0, stream>>>(cb, out, mask_);
    patch_ln_kernel<<<392, 256, 0, stream>>>(x, pw, pb, lng, lnb, pn_, pnsq_);

    kmeans_init_kernel<<<NBATCH, 256, 0, stream>>>(pn_, cent_, csq_);
    for (int it = 0; it < NITER; ++it) {
        kmeans_iter_kernel<<<dim3(4, NBATCH), 256, 0, stream>>>(
            pn_, pnsq_, cent_, csq_, gsums_, gcnt_);
        kmeans_newcent_kernel<<<NBATCH, 256, 0, stream>>>(
            gsums_, gcnt_, cent_, csq_);
    }
    kmeans_finalize_kernel<<<768, 256, 0, stream>>>(cent_, pos);

    gemm_qkv_kernel<<<dim3(3, 64), 256, 0, stream>>>(c0_, qw, kw, vw, qb, kb, vb,
                                                     Q_, K_, V_);
    attn_spectral_kernel<<<NBATCH, 256, 0, stream>>>(Q_, K_, V_, ew, eb, c2_);
    gemm_kernel<0><<<dim3(3, 64), 256, 0, stream>>>(c2_, nw, nb, c3_, 2048, DM, DM);
    gemm_kernel<1><<<dim3(3, 64), 256, 0, stream>>>(c3_, m1w, m1b, h_, 2048, DM, DM);
    gemm_kernel<0><<<dim3(3, 64), 256, 0, stream>>>(h_, m2w, m2b, c4_, 2048, DM, DM);
    simmask_kernel<<<NBATCH, 256, 0, stream>>>(c4_, mask_);
    merge_fb_kernel<<<NBATCH, 256, 0, stream>>>(c4_, mask_, fbw, fbb, fgw, fgb, c5_);
    cls_kernel<<<dim3(8, 4, 8), 256, 0, stream>>>(c5_, cw, out);
}

// Round 5
// 983.031 us; speedup vs baseline: 1.2655x; 1.2157x over previous
//
#include <hip/hip_runtime.h>
#include <math.h>

// Shapes (fixed by the problem)
#define NBATCH 128
#define NPTS   196     // 14*14 patches
#define DIN    768     // 3*16*16
#define DM     384
#define KCL    16
#define NEXP   8
#define NITER  10
#define NCLS   1000

// ---------------------------------------------------------------------------
// K0: init out = cb (classifier bias), zero the merge mask
// ---------------------------------------------------------------------------
__global__ __launch_bounds__(256) void init_kernel(const float* __restrict__ cb,
                                                   float* __restrict__ out,
                                                   int* __restrict__ mask) {
    int idx = blockIdx.x * 256 + threadIdx.x;
    if (idx < NBATCH * NCLS) {
        out[idx] = cb[idx % NCLS];
    } else if (idx < NBATCH * NCLS + 256) {
        mask[idx - NBATCH * NCLS] = 0;
    }
}

// ---------------------------------------------------------------------------
// K1: patch extraction + GEMM (25088x768 @ 768x384) + bias + LayerNorm + pnsq
// 512 threads (8 waves -> 12 waves/CU at grid 392), BM=64, BK=16, micro 8x6.
// Lane cg=tid&63 owns cols cg+64j (W reads = broadcast-pair b32, conflict-free;
// A reads wave-uniform b128). VALU-bound by design: per-CU per-kk VALU 288cy
// vs LDS ~190cy.
// ---------------------------------------------------------------------------
#define BKP 16
__global__ __launch_bounds__(512, 4) void patch_ln_kernel(
        const float* __restrict__ x, const float* __restrict__ pw,
        const float* __restrict__ pb, const float* __restrict__ lng,
        const float* __restrict__ lnb, float* __restrict__ pn,
        float* __restrict__ pnsq) {
    __shared__ float As[BKP * 68];   // [kk][row], 64 rows + 4 pad
    __shared__ float Ws[BKP * DM];   // [kk][col]
    const int tid = threadIdx.x;
    const int m0  = blockIdx.x * 64;
    const int rg  = tid >> 6;        // 8 row-groups of 8 rows (one wave each)
    const int cg  = tid & 63;        // 64 col-groups; cols cg + 64j
    // A-stage mapping (first 256 threads): 64 loader rows x 4 k-quads
    const int lr = (tid & 255) >> 2, kq = tid & 3;
    const int m  = m0 + lr;
    const int bi = m / NPTS, n = m - bi * NPTS;
    const int nh = n / 14, nwp = n - nh * 14;
    const float* xb = x + (size_t)bi * 150528 + (size_t)(nh * 16) * 224 + nwp * 16;

    float acc[8][6];
#pragma unroll
    for (int r = 0; r < 8; ++r)
#pragma unroll
        for (int j = 0; j < 6; ++j) acc[r][j] = 0.f;

    const float4* pw4 = (const float4*)pw;
    for (int kc = 0; kc < DIN; kc += BKP) {
        if (tid < 256) {   // stage A: one float4 (4 consecutive k, same row)
            int k = kc + kq * 4;
            int c = k >> 8, py = (k >> 4) & 15, px = k & 15;
            float4 xv = *(const float4*)(xb + c * 50176 + py * 224 + px);
            As[(kq * 4 + 0) * 68 + lr] = xv.x;
            As[(kq * 4 + 1) * 68 + lr] = xv.y;
            As[(kq * 4 + 2) * 68 + lr] = xv.z;
            As[(kq * 4 + 3) * 68 + lr] = xv.w;
        }
        // stage W: 16x384 floats = 1536 float4, 3 per thread (contiguous)
#pragma unroll
        for (int t = 0; t < 3; ++t) {
            int s = tid + t * 512;
            ((float4*)Ws)[s] = pw4[kc * 96 + s];
        }
        __syncthreads();
#pragma unroll 4
        for (int kk = 0; kk < BKP; ++kk) {
            float a[8];
            *(float4*)&a[0] = *(const float4*)&As[kk * 68 + rg * 8];
            *(float4*)&a[4] = *(const float4*)&As[kk * 68 + rg * 8 + 4];
            float w[6];
#pragma unroll
            for (int j = 0; j < 6; ++j) w[j] = Ws[kk * DM + cg + 64 * j];
#pragma unroll
            for (int r = 0; r < 8; ++r)
#pragma unroll
                for (int j = 0; j < 6; ++j) acc[r][j] += a[r] * w[j];
        }
        __syncthreads();
    }

    // epilogue: +bias, LayerNorm (two-pass), write pn and pnsq.
    // Wave rg holds all 384 cols of rows m0+rg*8..+7 across its 64 lanes.
    float gvv[6], bvv[6], pbv[6];
#pragma unroll
    for (int j = 0; j < 6; ++j) {
        pbv[j] = pb[cg + 64 * j];
        gvv[j] = lng[cg + 64 * j];
        bvv[j] = lnb[cg + 64 * j];
    }
#pragma unroll
    for (int r = 0; r < 8; ++r) {
        float vloc[6];
        float s = 0.f;
#pragma unroll
        for (int j = 0; j < 6; ++j) { vloc[j] = acc[r][j] + pbv[j]; s += vloc[j]; }
#pragma unroll
        for (int off = 32; off >= 1; off >>= 1) s += __shfl_xor(s, off);
        float mu = s * (1.0f / DM);
        float q = 0.f;
#pragma unroll
        for (int j = 0; j < 6; ++j) { float dd = vloc[j] - mu; q += dd * dd; }
#pragma unroll
        for (int off = 32; off >= 1; off >>= 1) q += __shfl_xor(q, off);
        float rstd = rsqrtf(q * (1.0f / DM) + 1e-5f);
        float ov[6];
        float ssq = 0.f;
#pragma unroll
        for (int j = 0; j < 6; ++j) {
            float p = (vloc[j] - mu) * rstd * gvv[j] + bvv[j];
            ov[j] = p; ssq += p * p;
        }
#pragma unroll
        for (int off = 32; off >= 1; off >>= 1) ssq += __shfl_xor(ssq, off);
        int mr = m0 + rg * 8 + r;
        float* dst = pn + (size_t)mr * DM + cg;
#pragma unroll
        for (int j = 0; j < 6; ++j) dst[64 * j] = ov[j];
        if (cg == 0) pnsq[mr] = ssq;
    }
}

// ---------------------------------------------------------------------------
// K2a: k-means init. centers = pn[13k], csq, cnt=0. One block per batch.
// ---------------------------------------------------------------------------
__global__ __launch_bounds__(256) void kmeans_init_kernel(
        const float* __restrict__ pn, float* __restrict__ cent,
        float* __restrict__ csq, int* __restrict__ cnt) {
    const int b = blockIdx.x, tid = threadIdx.x;
    const float* pnb = pn + (size_t)b * NPTS * DM;
    float* cb = cent + (size_t)b * KCL * DM;
    for (int i = tid; i < KCL * DM / 4; i += 256) {
        int k = i / (DM / 4), d4 = i - k * (DM / 4);
        ((float4*)cb)[i] = ((const float4*)(pnb + (size_t)(13 * k) * DM))[d4];
    }
    if (tid < 128) {
        int k = tid >> 3, sub = tid & 7;
        const float* row = pnb + (size_t)(13 * k) * DM + sub * 48;
        float ss = 0.f;
        for (int d = 0; d < 48; d += 4) {
            float4 v = *(const float4*)(row + d);
            ss += v.x * v.x + v.y * v.y + v.z * v.z + v.w * v.w;
        }
#pragma unroll
        for (int off = 4; off >= 1; off >>= 1) ss += __shfl_xor(ss, off);
        if (sub == 0) csq[b * KCL + k] = ss;
    }
    if (tid < KCL) cnt[b * KCL + tid] = 0;
}

// ---------------------------------------------------------------------------
// K2b: assignment (round-2 proven). grid (7 tiles, 128 batches). 8 threads
// per point, interleaved d4-chunks (conflict-free broadcast LDS reads).
// ---------------------------------------------------------------------------
__global__ __launch_bounds__(256) void kmeans_assign_kernel(
        const float* __restrict__ pn, const float* __restrict__ pnsq,
        const float* __restrict__ cent, const float* __restrict__ csq,
        int* __restrict__ asn, int* __restrict__ cnt) {
    __shared__ float cs[KCL * DM];   // 24 KB
    __shared__ float cq[KCL];
    const int b = blockIdx.y, tile = blockIdx.x, tid = threadIdx.x;
    const float* cb = cent + (size_t)b * KCL * DM;
    for (int i = tid; i < KCL * DM / 4; i += 256)
        ((float4*)cs)[i] = ((const float4*)cb)[i];
    if (tid < KCL) cq[tid] = csq[b * KCL + tid];
    __syncthreads();

    const int p = tid >> 3, sub = tid & 7;
    const int n = tile * 32 + p;
    if (n >= NPTS) return;
    const float4* prow = (const float4*)(pn + ((size_t)b * NPTS + n) * DM);

    float acc[KCL];
#pragma unroll
    for (int k = 0; k < KCL; ++k) acc[k] = 0.f;
#pragma unroll 2
    for (int i = 0; i < 12; ++i) {
        const int d4 = sub + 8 * i;         // bank-quad = 4*sub: conflict-free
        float4 pv = prow[d4];
#pragma unroll
        for (int k = 0; k < KCL; ++k) {
            const float4 c = *(const float4*)&cs[k * DM + d4 * 4];
            acc[k] += pv.x * c.x + pv.y * c.y + pv.z * c.z + pv.w * c.w;
        }
    }
    // reduce over the 8 sub-lanes (consecutive lanes)
#pragma unroll
    for (int k = 0; k < KCL; ++k) {
        float a = acc[k];
        a += __shfl_xor(a, 1);
        a += __shfl_xor(a, 2);
        a += __shfl_xor(a, 4);
        acc[k] = a;
    }
    if (sub == 0) {
        const float mp = pnsq[b * NPTS + n];
        float best = (mp - 2.0f * acc[0]) + cq[0];
        int bk = 0;
#pragma unroll
        for (int k = 1; k < KCL; ++k) {
            float v = (mp - 2.0f * acc[k]) + cq[k];
            if (v < best) { best = v; bk = k; }   // strict < keeps first min
        }
        asn[b * NPTS + n] = bk;
        atomicAdd(&cnt[b * KCL + bk], 1);
    }
}

// ---------------------------------------------------------------------------
// K2c: centers update (round-2 proven). grid (16 k, 128 batches). Ballot-
// compress matching points into wave masks; each thread owns a float2 column.
// ---------------------------------------------------------------------------
__global__ __launch_bounds__(256) void kmeans_update_kernel(
        const float* __restrict__ pn, const int* __restrict__ asn,
        int* __restrict__ cnt, float* __restrict__ cent,
        float* __restrict__ csq) {
    __shared__ unsigned long long msk[4];
    __shared__ float red[4];
    const int b = blockIdx.y, k = blockIdx.x, tid = threadIdx.x;

    int a = -1;
    if (tid < NPTS) a = asn[b * NPTS + tid];
    unsigned long long bal = __ballot(a == k);
    if ((tid & 63) == 0) msk[tid >> 6] = bal;
    __syncthreads();

    const int c = cnt[b * KCL + k];
    float sx = 0.f, sy = 0.f;
    const float* pnb = pn + (size_t)b * NPTS * DM + 2 * tid;
    if (tid < 192) {
#pragma unroll
        for (int w = 0; w < 4; ++w) {
            unsigned long long m = msk[w];
            while (m) {
                int nn = w * 64 + (int)__builtin_ctzll(m);
                m &= m - 1;
                float2 v = *(const float2*)(pnb + (size_t)nn * DM);
                sx += v.x; sy += v.y;
            }
        }
    }
    float* cr = cent + ((size_t)b * KCL + k) * DM + 2 * tid;
    float nx = 0.f, ny = 0.f;
    if (tid < 192) {
        if (c > 0) {
            float inv = 1.0f / (float)c;
            nx = sx * inv; ny = sy * inv;
        } else {
            nx = cr[0]; ny = cr[1];
        }
        cr[0] = nx; cr[1] = ny;
    }
    float ss = nx * nx + ny * ny;
#pragma unroll
    for (int off = 32; off >= 1; off >>= 1) ss += __shfl_xor(ss, off);
    if ((tid & 63) == 0) red[tid >> 6] = ss;
    __syncthreads();
    if (tid == 0) {
        csq[b * KCL + k] = red[0] + red[1] + red[2] + red[3];
        cnt[b * KCL + k] = 0;
    }
}

// ---------------------------------------------------------------------------
// K2d: finalize clusters0 = cent + pos (in place: cent aliases c0)
// ---------------------------------------------------------------------------
__global__ __launch_bounds__(256) void kmeans_finalize_kernel(
        float* __restrict__ cent, const float* __restrict__ pos) {
    int i = blockIdx.x * 256 + threadIdx.x;          // float4 index
    int within = i % (KCL * DM / 4);
    float4 cv = ((const float4*)cent)[i];
    float4 pv = ((const float4*)pos)[within];
    cv.x += pv.x; cv.y += pv.y; cv.z += pv.z; cv.w += pv.w;
    ((float4*)cent)[i] = cv;
}

// ---------------------------------------------------------------------------
// K3: fused QKV GEMM: 3 outputs from one A-tile staging. BM=32, BN=128, BK=32.
// ---------------------------------------------------------------------------
__global__ __launch_bounds__(256) void gemm_qkv_kernel(
        const float* __restrict__ A,
        const float* __restrict__ qw, const float* __restrict__ kw,
        const float* __restrict__ vw,
        const float* __restrict__ qb, const float* __restrict__ kb,
        const float* __restrict__ vb,
        float* __restrict__ Q, float* __restrict__ K, float* __restrict__ V) {
    __shared__ float As[32 * 32];
    __shared__ float Ws[3][32 * 128];
    const int n0 = blockIdx.x * 128;
    const int m0 = blockIdx.y * 32;
    const int tid = threadIdx.x;
    const int rg = tid >> 5, cg = tid & 31;
    const int arow = tid >> 3, akg = tid & 7;
    const float* W[3] = {qw, kw, vw};

    float acc[3][4][4];
#pragma unroll
    for (int g = 0; g < 3; ++g)
#pragma unroll
        for (int r = 0; r < 4; ++r)
#pragma unroll
            for (int j = 0; j < 4; ++j) acc[g][r][j] = 0.f;

    for (int kc = 0; kc < DM; kc += 32) {
        float4 av = *(const float4*)(A + (size_t)(m0 + arow) * DM + kc + akg * 4);
        As[(akg * 4 + 0) * 32 + arow] = av.x;
        As[(akg * 4 + 1) * 32 + arow] = av.y;
        As[(akg * 4 + 2) * 32 + arow] = av.z;
        As[(akg * 4 + 3) * 32 + arow] = av.w;
#pragma unroll
        for (int g = 0; g < 3; ++g)
#pragma unroll
            for (int t = 0; t < 4; ++t) {
                int s = tid + t * 256;
                int kk = s >> 5, c4i = s & 31;
                *(float4*)&Ws[g][kk * 128 + c4i * 4] =
                    *(const float4*)(W[g] + (size_t)(kc + kk) * DM + n0 + c4i * 4);
            }
        __syncthreads();
#pragma unroll 8
        for (int kk = 0; kk < 32; ++kk) {
            float4 a = *(const float4*)&As[kk * 32 + rg * 4];
            float ar[4] = {a.x, a.y, a.z, a.w};
#pragma unroll
            for (int g = 0; g < 3; ++g) {
                float4 w = *(const float4*)&Ws[g][kk * 128 + cg * 4];
                float wr[4] = {w.x, w.y, w.z, w.w};
#pragma unroll
                for (int r = 0; r < 4; ++r)
#pragma unroll
                    for (int j = 0; j < 4; ++j) acc[g][r][j] += ar[r] * wr[j];
            }
        }
        __syncthreads();
    }
    const float* B[3] = {qb, kb, vb};
    float* O[3] = {Q, K, V};
#pragma unroll
    for (int g = 0; g < 3; ++g) {
        float4 bv = *(const float4*)(B[g] + n0 + cg * 4);
        float bvr[4] = {bv.x, bv.y, bv.z, bv.w};
#pragma unroll
        for (int r = 0; r < 4; ++r) {
            float o[4];
#pragma unroll
            for (int j = 0; j < 4; ++j) o[j] = acc[g][r][j] + bvr[j];
            *(float4*)(O[g] + (size_t)(m0 + rg * 4 + r) * DM + n0 + cg * 4) =
                *(float4*)&o[0];
        }
    }
}

// ---------------------------------------------------------------------------
// Generic fp32 GEMM: out(MxN) = A(MxK) @ W(KxN) + bias, optional exact GELU.
// ---------------------------------------------------------------------------
template <int ACT>
__global__ __launch_bounds__(256) void gemm_kernel(
        const float* __restrict__ A, const float* __restrict__ W,
        const float* __restrict__ bias, float* __restrict__ out,
        int M, int N, int Kd) {
    __shared__ float As[32 * 32];
    __shared__ float Ws[32 * 128];
    const int n0 = blockIdx.x * 128;
    const int m0 = blockIdx.y * 32;
    const int tid = threadIdx.x;
    const int rg = tid >> 5, cg = tid & 31;
    const int arow = tid >> 3, akg = tid & 7;
    float acc[4][4];
#pragma unroll
    for (int r = 0; r < 4; ++r)
#pragma unroll
        for (int j = 0; j < 4; ++j) acc[r][j] = 0.f;

    for (int kc = 0; kc < Kd; kc += 32) {
        float4 av = *(const float4*)(A + (size_t)(m0 + arow) * Kd + kc + akg * 4);
        As[(akg * 4 + 0) * 32 + arow] = av.x;
        As[(akg * 4 + 1) * 32 + arow] = av.y;
        As[(akg * 4 + 2) * 32 + arow] = av.z;
        As[(akg * 4 + 3) * 32 + arow] = av.w;
#pragma unroll
        for (int t = 0; t < 4; ++t) {
            int s = tid + t * 256;
            int kk = s >> 5, c4i = s & 31;
            *(float4*)&Ws[kk * 128 + c4i * 4] =
                *(const float4*)(W + (size_t)(kc + kk) * N + n0 + c4i * 4);
        }
        __syncthreads();
#pragma unroll 16
        for (int kk = 0; kk < 32; ++kk) {
            float4 a = *(const float4*)&As[kk * 32 + rg * 4];
            float4 w = *(const float4*)&Ws[kk * 128 + cg * 4];
            float ar[4] = {a.x, a.y, a.z, a.w};
            float wr[4] = {w.x, w.y, w.z, w.w};
#pragma unroll
            for (int r = 0; r < 4; ++r)
#pragma unroll
                for (int j = 0; j < 4; ++j) acc[r][j] += ar[r] * wr[j];
        }
        __syncthreads();
    }
    float4 bv = *(const float4*)(bias + n0 + cg * 4);
    float bvr[4] = {bv.x, bv.y, bv.z, bv.w};
#pragma unroll
    for (int r = 0; r < 4; ++r) {
        float o[4];
#pragma unroll
        for (int j = 0; j < 4; ++j) {
            float v = acc[r][j] + bvr[j];
            if (ACT == 1) v = 0.5f * v * (1.0f + erff(v * 0.70710678118654752440f));
            o[j] = v;
        }
        *(float4*)(out + (size_t)(m0 + rg * 4 + r) * N + n0 + cg * 4) = *(float4*)&o[0];
    }
}

// ---------------------------------------------------------------------------
// K4: attention + expert softmax + spectral (L @ clusters). Block = 1 batch.
// ---------------------------------------------------------------------------
__global__ __launch_bounds__(256) void attn_spectral_kernel(
        const float* __restrict__ Qg, const float* __restrict__ Kg,
        const float* __restrict__ Vg, const float* __restrict__ ew,
        const float* __restrict__ eb, float* __restrict__ c2) {
    __shared__ float Qs[KCL * 388];   // Q, later C1
    __shared__ float Ks[KCL * 388];   // K, later V
    __shared__ float ewt[NEXP * 388]; // ew transposed [e][d]
    __shared__ float Ss[KCL * 17];
    __shared__ float hws[KCL * 9];
    __shared__ float rds[NEXP];
    __shared__ float Ls[NEXP * NEXP];
    const int b = blockIdx.x, tid = threadIdx.x;
    for (int idx = tid; idx < KCL * DM; idx += 256) {
        int i = idx / DM, d = idx - i * DM;
        size_t g = (size_t)b * KCL * DM + idx;
        Qs[i * 388 + d] = Qg[g];
        Ks[i * 388 + d] = Kg[g];
    }
    for (int idx = tid; idx < DM * NEXP; idx += 256) {
        int d = idx >> 3, e = idx & 7;
        ewt[e * 388 + d] = ew[idx];
    }
    __syncthreads();
    {   // S = Q K^T / sqrt(D), softmax rows
        int i = tid >> 4, j = tid & 15;
        float acc = 0.f;
        for (int d = 0; d < DM; d += 4) {
            float4 q = *(const float4*)&Qs[i * 388 + d];
            float4 k = *(const float4*)&Ks[j * 388 + d];
            acc += q.x * k.x + q.y * k.y + q.z * k.z + q.w * k.w;
        }
        float s = acc / sqrtf((float)DM);
        float mx = s;
#pragma unroll
        for (int off = 8; off >= 1; off >>= 1) mx = fmaxf(mx, __shfl_xor(mx, off));
        float p = expf(s - mx);
        float sm = p;
#pragma unroll
        for (int off = 8; off >= 1; off >>= 1) sm += __shfl_xor(sm, off);
        Ss[i * 17 + j] = p / sm;
    }
    __syncthreads();
    for (int idx = tid; idx < KCL * DM; idx += 256) {
        int i = idx / DM, d = idx - i * DM;
        Ks[i * 388 + d] = Vg[(size_t)b * KCL * DM + idx];
    }
    __syncthreads();
    for (int idx = tid; idx < KCL * DM; idx += 256) {
        int i = idx / DM, d = idx - i * DM;
        float acc = 0.f;
#pragma unroll
        for (int j = 0; j < KCL; ++j) acc += Ss[i * 17 + j] * Ks[j * 388 + d];
        Qs[i * 388 + d] = acc;
    }
    __syncthreads();
    if (tid < 128) {
        int e = tid >> 4, i = tid & 15;
        float l = 0.f;
        for (int d4 = 0; d4 < DM / 4; ++d4) {
            float4 q = *(const float4*)&Qs[i * 388 + d4 * 4];
            float4 w = *(const float4*)&ewt[e * 388 + d4 * 4];
            l += q.x * w.x + q.y * w.y + q.z * w.z + q.w * w.w;
        }
        l += eb[e];
        float mx = l;
#pragma unroll
        for (int off = 8; off >= 1; off >>= 1) mx = fmaxf(mx, __shfl_xor(mx, off));
        float p = expf(l - mx);
        float sm = p;
#pragma unroll
        for (int off = 8; off >= 1; off >>= 1) sm += __shfl_xor(sm, off);
        float h = p / sm;
        hws[i * 9 + e] = h;
        float sd = h;
#pragma unroll
        for (int off = 8; off >= 1; off >>= 1) sd += __shfl_xor(sd, off);
        if (i == 0) rds[e] = 1.0f / sqrtf(sd);
    }
    __syncthreads();
    if (tid < 64) {
        int e = tid >> 3, f = tid & 7;
        float gsum = 0.f;
#pragma unroll
        for (int k = 0; k < KCL; ++k) gsum += hws[k * 9 + e] * hws[k * 9 + f];
        Ls[e * 8 + f] = ((e == f) ? 1.0f : 0.0f) - rds[e] * gsum;
    }
    __syncthreads();
    for (int idx = tid; idx < KCL * DM; idx += 256) {
        int i = idx / DM, d = idx - i * DM;
        float acc = 0.f;
        if (i < NEXP) {
#pragma unroll
            for (int j = 0; j < NEXP; ++j) acc += Ls[i * 8 + j] * Qs[j * 388 + d];
        }
        c2[(size_t)b * KCL * DM + idx] = acc;
    }
}

// ---------------------------------------------------------------------------
// K6: normalize rows, sim = nc @ nc^T, OR (sim>0.9) into global mask
// ---------------------------------------------------------------------------
__global__ __launch_bounds__(256) void simmask_kernel(const float* __restrict__ c4,
                                                      int* __restrict__ mask) {
    __shared__ float Cs[KCL * 388];
    __shared__ float rns[KCL];
    const int b = blockIdx.x, tid = threadIdx.x;
    for (int idx = tid; idx < KCL * DM; idx += 256) {
        int i = idx / DM, d = idx - i * DM;
        Cs[i * 388 + d] = c4[(size_t)b * KCL * DM + idx];
    }
    __syncthreads();
    {
        int i = tid >> 4, s = tid & 15;
        float ss = 0.f;
        for (int t = 0; t < 24; ++t) { float v = Cs[i * 388 + s + 16 * t]; ss += v * v; }
#pragma unroll
        for (int off = 8; off >= 1; off >>= 1) ss += __shfl_xor(ss, off);
        if (s == 0) rns[i] = 1.0f / fmaxf(sqrtf(ss), 1e-12f);
    }
    __syncthreads();
    for (int idx = tid; idx < KCL * DM; idx += 256) {
        int i = idx / DM, d = idx - i * DM;
        Cs[i * 388 + d] *= rns[i];
    }
    __syncthreads();
    {
        int i = tid >> 4, j = tid & 15;
        if (j > i) {
            float dp = 0.f;
            for (int d = 0; d < DM; d += 4) {
                float4 a = *(const float4*)&Cs[i * 388 + d];
                float4 c = *(const float4*)&Cs[j * 388 + d];
                dp += a.x * c.x + a.y * c.y + a.z * c.z + a.w * c.w;
            }
            if (dp > 0.9f) atomicOr(&mask[i * KCL + j], 1);
        }
    }
}

// ---------------------------------------------------------------------------
// K7: sequential pairwise merge + mean + feedback gate -> c5
// ---------------------------------------------------------------------------
__global__ __launch_bounds__(256) void merge_fb_kernel(
        const float* __restrict__ c4, const int* __restrict__ mask,
        const float* __restrict__ fbw, const float* __restrict__ fbb,
        const float* __restrict__ fgw, const float* __restrict__ fgb,
        float* __restrict__ c5) {
    __shared__ int   mk[256];
    __shared__ float gs[DM];
    __shared__ float wred[3];
    __shared__ float gatev;
    const int b = blockIdx.x, tid = threadIdx.x;
    mk[tid] = mask[tid];
    const bool act = tid < 192;
    const int t = tid;
    float2 v[KCL];
    if (act) {
#pragma unroll
        for (int i = 0; i < KCL; ++i)
            v[i] = *(const float2*)(c4 + (size_t)b * KCL * DM + i * DM + 2 * t);
    }
    __syncthreads();
    if (act) {
#pragma unroll
        for (int i = 0; i < KCL; ++i)
#pragma unroll
            for (int j = i + 1; j < KCL; ++j)
                if (mk[i * KCL + j]) {
                    float mx = 0.5f * (v[i].x + v[j].x);
                    float my = 0.5f * (v[i].y + v[j].y);
                    v[i].x = mx; v[i].y = my; v[j].x = mx; v[j].y = my;
                }
    }
    float2 gv = {0.f, 0.f};
    if (act) {
#pragma unroll
        for (int i = 0; i < KCL; ++i) { gv.x += v[i].x; gv.y += v[i].y; }
        gv.x *= 0.0625f; gv.y *= 0.0625f;
        gs[2 * t] = gv.x; gs[2 * t + 1] = gv.y;
    }
    float pg = act ? (gv.x * fgw[2 * t] + gv.y * fgw[2 * t + 1]) : 0.f;
#pragma unroll
    for (int off = 32; off >= 1; off >>= 1) pg += __shfl_xor(pg, off);
    if (act && (tid & 63) == 0) wred[tid >> 6] = pg;
    __syncthreads();
    if (tid == 0) {
        float d = wred[0] + wred[1] + wred[2] + fgb[0];
        gatev = 1.0f / (1.0f + expf(-d));
    }
    __syncthreads();
    if (act) {
        float fx = fbb[2 * t], fy = fbb[2 * t + 1];
        for (int j = 0; j < DM; ++j) {
            float gj = gs[j];
            const float2 w = *(const float2*)(fbw + (size_t)j * DM + 2 * t);
            fx += gj * w.x; fy += gj * w.y;
        }
        float gt = gatev;
#pragma unroll
        for (int i = 0; i < KCL; ++i) {
            float2 o = {v[i].x + fx * gt, v[i].y + fy * gt};
            *(float2*)(c5 + (size_t)b * KCL * DM + i * DM + 2 * t) = o;
        }
    }
}

// ---------------------------------------------------------------------------
// K8: classifier, split-K with fp32 atomics. out pre-initialized with cb.
// ---------------------------------------------------------------------------
__global__ __launch_bounds__(256) void cls_kernel(const float* __restrict__ A,
                                                  const float* __restrict__ Wt,
                                                  float* __restrict__ out) {
    __shared__ float As[32 * 32];
    __shared__ float Ws[32 * 128];
    const int n0 = blockIdx.x * 128;
    const int m0 = blockIdx.y * 32;
    const int k0 = blockIdx.z * 768;
    const int tid = threadIdx.x;
    const int rg = tid >> 5, cg = tid & 31;
    const int arow = tid >> 3, akg = tid & 7;
    float acc[4][4];
#pragma unroll
    for (int r = 0; r < 4; ++r)
#pragma unroll
        for (int j = 0; j < 4; ++j) acc[r][j] = 0.f;

    for (int kc = k0; kc < k0 + 768; kc += 32) {
        float4 av = *(const float4*)(A + (size_t)(m0 + arow) * (KCL * DM) + kc + akg * 4);
        As[(akg * 4 + 0) * 32 + arow] = av.x;
        As[(akg * 4 + 1) * 32 + arow] = av.y;
        As[(akg * 4 + 2) * 32 + arow] = av.z;
        As[(akg * 4 + 3) * 32 + arow] = av.w;
#pragma unroll
        for (int ti = 0; ti < 4; ++ti) {
            int s = tid + ti * 256;
            int kk = s >> 5, c4i = s & 31;
            int col = n0 + c4i * 4;
            float4 wv = make_float4(0.f, 0.f, 0.f, 0.f);
            if (col < NCLS) wv = *(const float4*)(Wt + (size_t)(kc + kk) * NCLS + col);
            *(float4*)&Ws[kk * 128 + c4i * 4] = wv;
        }
        __syncthreads();
#pragma unroll 16
        for (int kk = 0; kk < 32; ++kk) {
            float4 a = *(const float4*)&As[kk * 32 + rg * 4];
            float4 w = *(const float4*)&Ws[kk * 128 + cg * 4];
            float ar[4] = {a.x, a.y, a.z, a.w};
            float wr[4] = {w.x, w.y, w.z, w.w};
#pragma unroll
            for (int r = 0; r < 4; ++r)
#pragma unroll
                for (int j = 0; j < 4; ++j) acc[r][j] += ar[r] * wr[j];
        }
        __syncthreads();
    }
    int col = n0 + cg * 4;
    if (col < NCLS) {
#pragma unroll
        for (int r = 0; r < 4; ++r) {
            int row = m0 + rg * 4 + r;
#pragma unroll
            for (int j = 0; j < 4; ++j)
                atomicAdd(&out[(size_t)row * NCLS + col + j], acc[r][j]);
        }
    }
}

// ---------------------------------------------------------------------------
extern "C" void kernel_launch(void* const* d_in, const int* in_sizes, int n_in,
                              void* d_out, int out_size, void* d_ws, size_t ws_size,
                              hipStream_t stream) {
    const float* x   = (const float*)d_in[0];
    const float* pw  = (const float*)d_in[1];
    const float* pb  = (const float*)d_in[2];
    const float* lng = (const float*)d_in[3];
    const float* lnb = (const float*)d_in[4];
    const float* pos = (const float*)d_in[5];
    const float* qw  = (const float*)d_in[6];
    const float* qb  = (const float*)d_in[7];
    const float* kw  = (const float*)d_in[8];
    const float* kb  = (const float*)d_in[9];
    const float* vw  = (const float*)d_in[10];
    const float* vb  = (const float*)d_in[11];
    const float* ew  = (const float*)d_in[12];
    const float* eb  = (const float*)d_in[13];
    const float* nw  = (const float*)d_in[14];
    const float* nb  = (const float*)d_in[15];
    const float* m1w = (const float*)d_in[16];
    const float* m1b = (const float*)d_in[17];
    const float* m2w = (const float*)d_in[18];
    const float* m2b = (const float*)d_in[19];
    const float* fbw = (const float*)d_in[20];
    const float* fbb = (const float*)d_in[21];
    const float* fgw = (const float*)d_in[22];
    const float* fgb = (const float*)d_in[23];
    const float* cw  = (const float*)d_in[24];
    const float* cb  = (const float*)d_in[25];
    float* out = (float*)d_out;
    float* ws  = (float*)d_ws;

    // workspace layout (floats)
    float* pn_   = ws;                    // 128*196*384 = 9,633,792
    float* pnsq_ = ws + 9633792;          // 25,088
    float* c0_   = ws + 9658880;          // 786,432 (kmeans centers; then clusters0; later c5)
    float* Q_    = ws + 10445312;         // 786,432 (later c3)
    float* K_    = ws + 11231744;         // 786,432 (later h)
    float* V_    = ws + 12018176;         // 786,432 (later c4)
    float* c2_   = ws + 12804608;         // 786,432
    int*   mask_ = (int*)(ws + 13591040); // 256 ints
    float* csq_  = ws + 13591296;         // 2048
    int*   cnt_  = (int*)(ws + 13593344); // 2048 ints
    int*   asn_  = (int*)(ws + 13595392); // 25,088 ints
    float* cent_ = c0_;                   // centers evolve in place, become c0
    float* c3_ = Q_;
    float* h_  = K_;
    float* c4_ = V_;
    float* c5_ = c0_;

    init_kernel<<<501, 256, 0, stream>>>(cb, out, mask_);
    patch_ln_kernel<<<392, 512, 0, stream>>>(x, pw, pb, lng, lnb, pn_, pnsq_);

    kmeans_init_kernel<<<NBATCH, 256, 0, stream>>>(pn_, cent_, csq_, cnt_);
    for (int it = 0; it < NITER; ++it) {
        kmeans_assign_kernel<<<dim3(7, NBATCH), 256, 0, stream>>>(
            pn_, pnsq_, cent_, csq_, asn_, cnt_);
        kmeans_update_kernel<<<dim3(KCL, NBATCH), 256, 0, stream>>>(
            pn_, asn_, cnt_, cent_, csq_);
    }
    kmeans_finalize_kernel<<<768, 256, 0, stream>>>(cent_, pos);

    gemm_qkv_kernel<<<dim3(3, 64), 256, 0, stream>>>(c0_, qw, kw, vw, qb, kb, vb,
                                                     Q_, K_, V_);
    attn_spectral_kernel<<<NBATCH, 256, 0, stream>>>(Q_, K_, V_, ew, eb, c2_);
    gemm_kernel<0><<<dim3(3, 64), 256, 0, stream>>>(c2_, nw, nb, c3_, 2048, DM, DM);
    gemm_kernel<1><<<dim3(3, 64), 256, 0, stream>>>(c3_, m1w, m1b, h_, 2048, DM, DM);
    gemm_kernel<0><<<dim3(3, 64), 256, 0, stream>>>(h_, m2w, m2b, c4_, 2048, DM, DM);
    simmask_kernel<<<NBATCH, 256, 0, stream>>>(c4_, mask_);
    merge_fb_kernel<<<NBATCH, 256, 0, stream>>>(c4_, mask_, fbw, fbb, fgw, fgb, c5_);
    cls_kernel<<<dim3(8, 4, 8), 256, 0, stream>>>(c5_, cw, out);
}